// Round 1
// baseline (929.981 us; speedup 1.0000x reference)
//
#include <hip/hip_runtime.h>

#define NN 50000
#define NE 800000
#define BG 512
#define HD 128
#define GD 32
#define MD 128
#define EPSV 1e-5f

// ---------------- CSR build ----------------
__global__ void k_count(const int* __restrict__ dst, int* __restrict__ counts) {
    int e = blockIdx.x * blockDim.x + threadIdx.x;
    if (e < NE) atomicAdd(&counts[dst[e]], 1);
}

// single block, 1024 threads: exclusive scan of counts -> offsets, and dinv
__global__ void k_scan(const int* __restrict__ counts, int* __restrict__ offsets,
                       float* __restrict__ dinv) {
    __shared__ int part[1024];
    const int CH = (NN + 1023) / 1024; // 49
    int tid = threadIdx.x;
    int base = tid * CH;
    int s = 0;
    for (int j = 0; j < CH; ++j) {
        int i = base + j;
        if (i < NN) s += counts[i];
    }
    part[tid] = s;
    __syncthreads();
    // Hillis-Steele inclusive scan over 1024 partials
    for (int off = 1; off < 1024; off <<= 1) {
        int v = part[tid];
        int add = (tid >= off) ? part[tid - off] : 0;
        __syncthreads();
        part[tid] = v + add;
        __syncthreads();
    }
    int run = (tid == 0) ? 0 : part[tid - 1];
    for (int j = 0; j < CH; ++j) {
        int i = base + j;
        if (i < NN) {
            offsets[i] = run;
            int c = counts[i];
            run += c;
            dinv[i] = rsqrtf((float)(c + 1)); // in-degree + self loop
        }
    }
    if (tid == 0) offsets[NN] = NE;
}

__global__ void k_fill(const int* __restrict__ src, const int* __restrict__ dst,
                       int* __restrict__ cursor, int* __restrict__ csr) {
    int e = blockIdx.x * blockDim.x + threadIdx.x;
    if (e < NE) {
        int d = dst[e];
        int p = atomicAdd(&cursor[d], 1);
        csr[p] = src[e];
    }
}

// ---------------- GEMM: T = In @ W  (In: [NN,128], W: [128,128]) ----------------
// 64 rows x 128 cols per block, 256 threads, 8x4 register tile, K chunks of 32.
__global__ __launch_bounds__(256) void k_gemm(const float* __restrict__ In,
                                              const float* __restrict__ W,
                                              float* __restrict__ T) {
    __shared__ float As[32][64];   // transposed: [k][row]
    __shared__ float Ws[32][128];  // [k][col]
    int tid = threadIdx.x;
    int rowBase = blockIdx.x * 64;
    int r0 = (tid >> 5) * 8;
    int c0 = (tid & 31) * 4;
    float acc[8][4];
#pragma unroll
    for (int i = 0; i < 8; ++i)
#pragma unroll
        for (int j = 0; j < 4; ++j) acc[i][j] = 0.f;

    for (int k0 = 0; k0 < HD; k0 += 32) {
        // stage A chunk: 64 rows x 32 k = 512 float4, 2 per thread
#pragma unroll
        for (int t = 0; t < 2; ++t) {
            int q = tid + t * 256;     // [0,512)
            int row = q & 63;          // lane-major rows -> conflict-free LDS store
            int kq = q >> 6;           // [0,8)
            int rg = rowBase + row;
            if (rg >= NN) rg = NN - 1; // clamp; ghost rows never stored
            float4 v = *(const float4*)&In[(size_t)rg * HD + k0 + kq * 4];
            As[kq * 4 + 0][row] = v.x;
            As[kq * 4 + 1][row] = v.y;
            As[kq * 4 + 2][row] = v.z;
            As[kq * 4 + 3][row] = v.w;
        }
        // stage W chunk: 32 k x 128 cols = 1024 float4, 4 per thread
#pragma unroll
        for (int t = 0; t < 4; ++t) {
            int q = tid + t * 256;     // [0,1024)
            int kk = q >> 5;
            int c4 = (q & 31) * 4;
            *(float4*)&Ws[kk][c4] = *(const float4*)&W[(size_t)(k0 + kk) * HD + c4];
        }
        __syncthreads();
#pragma unroll
        for (int kk = 0; kk < 32; ++kk) {
            float4 a0 = *(const float4*)&As[kk][r0];
            float4 a1 = *(const float4*)&As[kk][r0 + 4];
            float4 w = *(const float4*)&Ws[kk][c0];
            float av[8] = {a0.x, a0.y, a0.z, a0.w, a1.x, a1.y, a1.z, a1.w};
            float wv[4] = {w.x, w.y, w.z, w.w};
#pragma unroll
            for (int i = 0; i < 8; ++i)
#pragma unroll
                for (int j = 0; j < 4; ++j) acc[i][j] += av[i] * wv[j];
        }
        __syncthreads();
    }
#pragma unroll
    for (int i = 0; i < 8; ++i) {
        int row = rowBase + r0 + i;
        if (row < NN) {
            float4 o = {acc[i][0], acc[i][1], acc[i][2], acc[i][3]};
            *(float4*)&T[(size_t)row * HD + c0] = o;
        }
    }
}

// ---------------- Aggregate: A[d] = dinv[d]*sum_e dinv[s]*T[s] + dinv[d]^2*T[d] + b ----------------
__global__ __launch_bounds__(256) void k_aggregate(const float* __restrict__ T,
                                                   const int* __restrict__ offsets,
                                                   const int* __restrict__ csr,
                                                   const float* __restrict__ dinv,
                                                   const float* __restrict__ bias,
                                                   float* __restrict__ A) {
    int d = blockIdx.x * 2 + (threadIdx.x >> 7);
    int f = threadIdx.x & 127;
    if (d >= NN) return;
    int start = offsets[d], end = offsets[d + 1];
    float acc = 0.f;
    int j = start;
    for (; j + 1 < end; j += 2) {
        int s0 = csr[j], s1 = csr[j + 1];
        float w0 = dinv[s0], w1 = dinv[s1];
        float v0 = T[(size_t)s0 * HD + f];
        float v1 = T[(size_t)s1 * HD + f];
        acc += w0 * v0;
        acc += w1 * v1;
    }
    if (j < end) {
        int s0 = csr[j];
        acc += dinv[s0] * T[(size_t)s0 * HD + f];
    }
    float di = dinv[d];
    float out = di * acc + di * di * T[(size_t)d * HD + f] + bias[f];
    A[(size_t)d * HD + f] = out;
}

// ---------------- BN stats: column sum & sumsq ----------------
__global__ __launch_bounds__(256) void k_colstats(const float* __restrict__ A,
                                                  float* __restrict__ stats) {
    int f = threadIdx.x & 127;
    int half = threadIdx.x >> 7;
    float s = 0.f, sq = 0.f;
    for (int row = blockIdx.x * 2 + half; row < NN; row += gridDim.x * 2) {
        float v = A[(size_t)row * HD + f];
        s += v;
        sq += v * v;
    }
    __shared__ float ls[256], lq[256];
    ls[threadIdx.x] = s;
    lq[threadIdx.x] = sq;
    __syncthreads();
    if (half == 0) {
        atomicAdd(&stats[f], ls[f] + ls[f + 128]);
        atomicAdd(&stats[128 + f], lq[f] + lq[f + 128]);
    }
}

__global__ void k_bnfinal(const float* __restrict__ stats, const float* __restrict__ gamma,
                          const float* __restrict__ beta, float* __restrict__ ss) {
    int c = threadIdx.x;
    if (c < HD) {
        float mu = stats[c] * (1.f / NN);
        float var = stats[128 + c] * (1.f / NN) - mu * mu;
        float sc = gamma[c] * rsqrtf(var + EPSV);
        ss[c] = sc;
        ss[128 + c] = beta[c] - mu * sc;
    }
}

__global__ void k_bnrelu(float* __restrict__ A, const float* __restrict__ ss) {
    int idx = blockIdx.x * blockDim.x + threadIdx.x; // float4 index
    if (idx >= NN * HD / 4) return;
    int c = (idx & 31) * 4;
    float4 v = ((float4*)A)[idx];
    float s0 = ss[c], s1 = ss[c + 1], s2 = ss[c + 2], s3 = ss[c + 3];
    float h0 = ss[128 + c], h1 = ss[128 + c + 1], h2 = ss[128 + c + 2], h3 = ss[128 + c + 3];
    v.x = fmaxf(v.x * s0 + h0, 0.f);
    v.y = fmaxf(v.y * s1 + h1, 0.f);
    v.z = fmaxf(v.z * s2 + h2, 0.f);
    v.w = fmaxf(v.w * s3 + h3, 0.f);
    ((float4*)A)[idx] = v;
}

// ---------------- Pool ----------------
__global__ void k_pool(const float* __restrict__ A, const int* __restrict__ batch,
                       float* __restrict__ pooled, float* __restrict__ cnt) {
    int idx = blockIdx.x * blockDim.x + threadIdx.x;
    if (idx >= NN * HD) return;
    int node = idx >> 7, f = idx & 127;
    int bb = batch[node];
    atomicAdd(&pooled[(size_t)bb * HD + f], A[idx]);
    if (f == 0) atomicAdd(&cnt[bb], 1.f);
}

// ---------------- MLP head ----------------
__global__ __launch_bounds__(128) void k_mlp(const float* __restrict__ pooled,
                                             const float* __restrict__ cnt,
                                             const float* __restrict__ gfeat,
                                             const float* __restrict__ M1w,
                                             const float* __restrict__ M1b,
                                             const float* __restrict__ M2w,
                                             const float* __restrict__ M2b,
                                             const float* __restrict__ M3w,
                                             const float* __restrict__ M3b,
                                             float* __restrict__ out) {
    __shared__ float z[HD + GD];
    __shared__ float z1[MD];
    __shared__ float z2[MD / 2];
    int b = blockIdx.x, t = threadIdx.x;
    float ic = 1.f / fmaxf(cnt[b], 1.f);
    z[t] = pooled[(size_t)b * HD + t] * ic;
    if (t < GD) z[HD + t] = gfeat[b * GD + t];
    __syncthreads();
    float a = M1b[t];
    for (int k = 0; k < HD + GD; ++k) a += z[k] * M1w[k * MD + t];
    z1[t] = fmaxf(a, 0.f);
    __syncthreads();
    if (t < MD / 2) {
        float a2 = M2b[t];
        for (int k = 0; k < MD; ++k) a2 += z1[k] * M2w[k * (MD / 2) + t];
        z2[t] = fmaxf(a2, 0.f);
    }
    __syncthreads();
    if (t < 64) {
        float p = z2[t] * M3w[t];
#pragma unroll
        for (int off = 32; off; off >>= 1) p += __shfl_down(p, off);
        if (t == 0) out[b] = p + M3b[0];
    }
}

static inline size_t alg(size_t x) { return (x + 255) & ~(size_t)255; }

extern "C" void kernel_launch(void* const* d_in, const int* in_sizes, int n_in,
                              void* d_out, int out_size, void* d_ws, size_t ws_size,
                              hipStream_t stream) {
    const float* x = (const float*)d_in[0];
    const int* ei = (const int*)d_in[1];
    const int* batch = (const int*)d_in[2];
    const float* gf = (const float*)d_in[3];
    const float* W[3] = {(const float*)d_in[4], (const float*)d_in[8], (const float*)d_in[12]};
    const float* bb[3] = {(const float*)d_in[5], (const float*)d_in[9], (const float*)d_in[13]};
    const float* gg[3] = {(const float*)d_in[6], (const float*)d_in[10], (const float*)d_in[14]};
    const float* be[3] = {(const float*)d_in[7], (const float*)d_in[11], (const float*)d_in[15]};
    const float* M1w = (const float*)d_in[16];
    const float* M1b = (const float*)d_in[17];
    const float* M2w = (const float*)d_in[18];
    const float* M2b = (const float*)d_in[19];
    const float* M3w = (const float*)d_in[20];
    const float* M3b = (const float*)d_in[21];
    float* out = (float*)d_out;

    char* w = (char*)d_ws;
    int* counts = (int*)w;      w += alg((size_t)NN * 4);
    int* offsets = (int*)w;     w += alg((size_t)(NN + 1) * 4);
    int* cursor = (int*)w;      w += alg((size_t)NN * 4);
    int* csr = (int*)w;         w += alg((size_t)NE * 4);
    float* dinv = (float*)w;    w += alg((size_t)NN * 4);
    float* stats = (float*)w;   w += alg(256 * 4);
    float* ss = (float*)w;      w += alg(256 * 4);
    float* pooled = (float*)w;  w += alg((size_t)BG * HD * 4 + (size_t)BG * 4);
    float* cnt = pooled + (size_t)BG * HD;
    float* A = (float*)w;       w += alg((size_t)NN * HD * 4);
    float* T = (float*)w;       w += alg((size_t)NN * HD * 4);

    const int* src = ei;
    const int* dst = ei + NE;

    hipMemsetAsync(counts, 0, (size_t)NN * 4, stream);
    k_count<<<(NE + 255) / 256, 256, 0, stream>>>(dst, counts);
    k_scan<<<1, 1024, 0, stream>>>(counts, offsets, dinv);
    hipMemcpyAsync(cursor, offsets, (size_t)NN * 4, hipMemcpyDeviceToDevice, stream);
    k_fill<<<(NE + 255) / 256, 256, 0, stream>>>(src, dst, cursor, csr);

    const float* hin = x;
    for (int L = 0; L < 3; ++L) {
        k_gemm<<<(NN + 63) / 64, 256, 0, stream>>>(hin, W[L], T);
        hipMemsetAsync(stats, 0, 256 * 4, stream);
        k_aggregate<<<(NN + 1) / 2, 256, 0, stream>>>(T, offsets, csr, dinv, bb[L], A);
        k_colstats<<<256, 256, 0, stream>>>(A, stats);
        k_bnfinal<<<1, 128, 0, stream>>>(stats, gg[L], be[L], ss);
        k_bnrelu<<<(NN * HD / 4 + 255) / 256, 256, 0, stream>>>(A, ss);
        hin = A;
    }

    hipMemsetAsync(pooled, 0, (size_t)(BG * HD + BG) * 4, stream);
    k_pool<<<(NN * HD + 255) / 256, 256, 0, stream>>>(A, batch, pooled, cnt);
    k_mlp<<<BG, 128, 0, stream>>>(pooled, cnt, gf, M1w, M1b, M2w, M2b, M3w, M3b, out);
}

// Round 2
// 724.616 us; speedup vs baseline: 1.2834x; 1.2834x over previous
//
#include <hip/hip_runtime.h>

#define NN 50000
#define NE 800000
#define BG 512
#define HD 128
#define GD 32
#define MD 128
#define EPSV 1e-5f
#define SCB 196  // ceil(NN/256) scan blocks

// ---------------- CSR build ----------------
__global__ void k_count(const int* __restrict__ dst, int* __restrict__ counts) {
    int e = blockIdx.x * blockDim.x + threadIdx.x;
    if (e < NE) atomicAdd(&counts[dst[e]], 1);
}

// phase 1: per-block sums of counts
__global__ __launch_bounds__(256) void k_bsum(const int* __restrict__ counts,
                                              int* __restrict__ bsum) {
    __shared__ int ls[256];
    int i = blockIdx.x * 256 + threadIdx.x;
    ls[threadIdx.x] = (i < NN) ? counts[i] : 0;
    __syncthreads();
    for (int off = 128; off; off >>= 1) {
        if (threadIdx.x < off) ls[threadIdx.x] += ls[threadIdx.x + off];
        __syncthreads();
    }
    if (threadIdx.x == 0) bsum[blockIdx.x] = ls[0];
}

// phase 2: single small block scans the SCB partials -> exclusive prefixes
__global__ __launch_bounds__(256) void k_bscan(const int* __restrict__ bsum,
                                               int* __restrict__ bpre) {
    __shared__ int ls[256];
    int t = threadIdx.x;
    int v = (t < SCB) ? bsum[t] : 0;
    ls[t] = v;
    __syncthreads();
    for (int off = 1; off < 256; off <<= 1) {
        int cur = ls[t];
        int add = (t >= off) ? ls[t - off] : 0;
        __syncthreads();
        ls[t] = cur + add;
        __syncthreads();
    }
    if (t < SCB) bpre[t] = ls[t] - v;  // exclusive
}

// phase 3: local exclusive scan + block prefix -> offsets, cursor, dinv
__global__ __launch_bounds__(256) void k_offsets(const int* __restrict__ counts,
                                                 const int* __restrict__ bpre,
                                                 int* __restrict__ offsets,
                                                 int* __restrict__ cursor,
                                                 float* __restrict__ dinv) {
    __shared__ int ls[256];
    int t = threadIdx.x;
    int i = blockIdx.x * 256 + t;
    int c = (i < NN) ? counts[i] : 0;
    ls[t] = c;
    __syncthreads();
    for (int off = 1; off < 256; off <<= 1) {
        int cur = ls[t];
        int add = (t >= off) ? ls[t - off] : 0;
        __syncthreads();
        ls[t] = cur + add;
        __syncthreads();
    }
    if (i < NN) {
        int excl = ls[t] - c + bpre[blockIdx.x];
        offsets[i] = excl;
        cursor[i] = excl;
        dinv[i] = rsqrtf((float)(c + 1));  // in-degree + self loop
        if (i == NN - 1) offsets[NN] = NE;
    }
}

__global__ void k_fill(const int* __restrict__ src, const int* __restrict__ dst,
                       int* __restrict__ cursor, int* __restrict__ csr) {
    int e = blockIdx.x * blockDim.x + threadIdx.x;
    if (e < NE) {
        int d = dst[e];
        int p = atomicAdd(&cursor[d], 1);
        csr[p] = src[e];
    }
}

// ---------------- GEMM: T = BNReLU?(In) @ W ----------------
// 64 rows x 128 cols per block, 256 threads, 8x4 register tile, K chunks of 32.
// If useBN, applies v = max(v*ss[c] + ss[128+c], 0) on the A-load (fused BN+ReLU
// of the previous layer).
__global__ __launch_bounds__(256) void k_gemm(const float* __restrict__ In,
                                              const float* __restrict__ W,
                                              float* __restrict__ T,
                                              const float* __restrict__ ss,
                                              int useBN) {
    __shared__ float As[32][64];   // transposed: [k][row]
    __shared__ float Ws[32][128];  // [k][col]
    int tid = threadIdx.x;
    int rowBase = blockIdx.x * 64;
    int r0 = (tid >> 5) * 8;
    int c0 = (tid & 31) * 4;
    float acc[8][4];
#pragma unroll
    for (int i = 0; i < 8; ++i)
#pragma unroll
        for (int j = 0; j < 4; ++j) acc[i][j] = 0.f;

    for (int k0 = 0; k0 < HD; k0 += 32) {
        // stage A chunk: 64 rows x 32 k = 512 float4, 2 per thread
#pragma unroll
        for (int t = 0; t < 2; ++t) {
            int q = tid + t * 256;     // [0,512)
            int row = q & 63;          // lane-major rows -> conflict-free LDS store
            int kq = q >> 6;           // [0,8)
            int rg = rowBase + row;
            if (rg >= NN) rg = NN - 1; // clamp; ghost rows never stored to T
            int col = k0 + kq * 4;
            float4 v = *(const float4*)&In[(size_t)rg * HD + col];
            if (useBN) {
                float4 s = *(const float4*)&ss[col];
                float4 h = *(const float4*)&ss[128 + col];
                v.x = fmaxf(v.x * s.x + h.x, 0.f);
                v.y = fmaxf(v.y * s.y + h.y, 0.f);
                v.z = fmaxf(v.z * s.z + h.z, 0.f);
                v.w = fmaxf(v.w * s.w + h.w, 0.f);
            }
            As[col - k0 + 0][row] = v.x;
            As[col - k0 + 1][row] = v.y;
            As[col - k0 + 2][row] = v.z;
            As[col - k0 + 3][row] = v.w;
        }
        // stage W chunk: 32 k x 128 cols = 1024 float4, 4 per thread
#pragma unroll
        for (int t = 0; t < 4; ++t) {
            int q = tid + t * 256;     // [0,1024)
            int kk = q >> 5;
            int c4 = (q & 31) * 4;
            *(float4*)&Ws[kk][c4] = *(const float4*)&W[(size_t)(k0 + kk) * HD + c4];
        }
        __syncthreads();
#pragma unroll
        for (int kk = 0; kk < 32; ++kk) {
            float4 a0 = *(const float4*)&As[kk][r0];
            float4 a1 = *(const float4*)&As[kk][r0 + 4];
            float4 w = *(const float4*)&Ws[kk][c0];
            float av[8] = {a0.x, a0.y, a0.z, a0.w, a1.x, a1.y, a1.z, a1.w};
            float wv[4] = {w.x, w.y, w.z, w.w};
#pragma unroll
            for (int i = 0; i < 8; ++i)
#pragma unroll
                for (int j = 0; j < 4; ++j) acc[i][j] += av[i] * wv[j];
        }
        __syncthreads();
    }
#pragma unroll
    for (int i = 0; i < 8; ++i) {
        int row = rowBase + r0 + i;
        if (row < NN) {
            float4 o = {acc[i][0], acc[i][1], acc[i][2], acc[i][3]};
            *(float4*)&T[(size_t)row * HD + c0] = o;
        }
    }
}

// ---------------- Aggregate: A[d] = dinv[d]*sum_e dinv[s]*T[s] + dinv[d]^2*T[d] + b ----------------
__global__ __launch_bounds__(256) void k_aggregate(const float* __restrict__ T,
                                                   const int* __restrict__ offsets,
                                                   const int* __restrict__ csr,
                                                   const float* __restrict__ dinv,
                                                   const float* __restrict__ bias,
                                                   float* __restrict__ A) {
    int d = blockIdx.x * 2 + (threadIdx.x >> 7);
    int f = threadIdx.x & 127;
    if (d >= NN) return;
    int start = offsets[d], end = offsets[d + 1];
    float acc = 0.f;
    int j = start;
    for (; j + 1 < end; j += 2) {
        int s0 = csr[j], s1 = csr[j + 1];
        float w0 = dinv[s0], w1 = dinv[s1];
        float v0 = T[(size_t)s0 * HD + f];
        float v1 = T[(size_t)s1 * HD + f];
        acc += w0 * v0;
        acc += w1 * v1;
    }
    if (j < end) {
        int s0 = csr[j];
        acc += dinv[s0] * T[(size_t)s0 * HD + f];
    }
    float di = dinv[d];
    float out = di * acc + di * di * T[(size_t)d * HD + f] + bias[f];
    A[(size_t)d * HD + f] = out;
}

// ---------------- BN stats: column sum & sumsq over raw A ----------------
__global__ __launch_bounds__(256) void k_colstats(const float* __restrict__ A,
                                                  float* __restrict__ stats) {
    int f = threadIdx.x & 127;
    int half = threadIdx.x >> 7;
    float s = 0.f, sq = 0.f;
    for (int row = blockIdx.x * 2 + half; row < NN; row += gridDim.x * 2) {
        float v = A[(size_t)row * HD + f];
        s += v;
        sq += v * v;
    }
    __shared__ float ls[256], lq[256];
    ls[threadIdx.x] = s;
    lq[threadIdx.x] = sq;
    __syncthreads();
    if (half == 0) {
        atomicAdd(&stats[f], ls[f] + ls[f + 128]);
        atomicAdd(&stats[128 + f], lq[f] + lq[f + 128]);
    }
}

__global__ void k_bnfinal(const float* __restrict__ stats, const float* __restrict__ gamma,
                          const float* __restrict__ beta, float* __restrict__ ss) {
    int c = threadIdx.x;
    if (c < HD) {
        float mu = stats[c] * (1.f / NN);
        float var = stats[128 + c] * (1.f / NN) - mu * mu;
        float sc = gamma[c] * rsqrtf(var + EPSV);
        ss[c] = sc;
        ss[128 + c] = beta[c] - mu * sc;
    }
}

// ---------------- Fused pool (+BN of layer 2) + MLP head ----------------
// batch is sorted, so graph b's nodes are the contiguous range
// [lower_bound(b), lower_bound(b+1)).
__global__ __launch_bounds__(128) void k_poolmlp(const float* __restrict__ A,
                                                 const int* __restrict__ batch,
                                                 const float* __restrict__ ss,
                                                 const float* __restrict__ gfeat,
                                                 const float* __restrict__ M1w,
                                                 const float* __restrict__ M1b,
                                                 const float* __restrict__ M2w,
                                                 const float* __restrict__ M2b,
                                                 const float* __restrict__ M3w,
                                                 const float* __restrict__ M3b,
                                                 float* __restrict__ out) {
    __shared__ int sb[2];
    __shared__ float z[HD + GD];
    __shared__ float z1[MD];
    __shared__ float z2[MD / 2];
    int b = blockIdx.x, t = threadIdx.x;
    if (t < 2) {
        int val = b + t;
        int lo = 0, hi = NN;
        while (lo < hi) {
            int mid = (lo + hi) >> 1;
            if (batch[mid] < val) lo = mid + 1; else hi = mid;
        }
        sb[t] = lo;
    }
    __syncthreads();
    int start = sb[0], end = sb[1];
    float s = ss[t], h = ss[128 + t];
    float acc = 0.f;
    for (int r = start; r < end; ++r)
        acc += fmaxf(A[(size_t)r * HD + t] * s + h, 0.f);
    float ic = 1.f / fmaxf((float)(end - start), 1.f);
    z[t] = acc * ic;
    if (t < GD) z[HD + t] = gfeat[b * GD + t];
    __syncthreads();
    float a = M1b[t];
    for (int k = 0; k < HD + GD; ++k) a += z[k] * M1w[k * MD + t];
    z1[t] = fmaxf(a, 0.f);
    __syncthreads();
    if (t < MD / 2) {
        float a2 = M2b[t];
        for (int k = 0; k < MD; ++k) a2 += z1[k] * M2w[k * (MD / 2) + t];
        z2[t] = fmaxf(a2, 0.f);
    }
    __syncthreads();
    if (t < 64) {
        float p = z2[t] * M3w[t];
#pragma unroll
        for (int off = 32; off; off >>= 1) p += __shfl_down(p, off);
        if (t == 0) out[b] = p + M3b[0];
    }
}

static inline size_t alg(size_t x) { return (x + 255) & ~(size_t)255; }

extern "C" void kernel_launch(void* const* d_in, const int* in_sizes, int n_in,
                              void* d_out, int out_size, void* d_ws, size_t ws_size,
                              hipStream_t stream) {
    const float* x = (const float*)d_in[0];
    const int* ei = (const int*)d_in[1];
    const int* batch = (const int*)d_in[2];
    const float* gf = (const float*)d_in[3];
    const float* W[3] = {(const float*)d_in[4], (const float*)d_in[8], (const float*)d_in[12]};
    const float* bb[3] = {(const float*)d_in[5], (const float*)d_in[9], (const float*)d_in[13]};
    const float* gg[3] = {(const float*)d_in[6], (const float*)d_in[10], (const float*)d_in[14]};
    const float* be[3] = {(const float*)d_in[7], (const float*)d_in[11], (const float*)d_in[15]};
    const float* M1w = (const float*)d_in[16];
    const float* M1b = (const float*)d_in[17];
    const float* M2w = (const float*)d_in[18];
    const float* M2b = (const float*)d_in[19];
    const float* M3w = (const float*)d_in[20];
    const float* M3b = (const float*)d_in[21];
    float* out = (float*)d_out;

    char* w = (char*)d_ws;
    int* counts = (int*)w;      w += alg((size_t)NN * 4);
    int* offsets = (int*)w;     w += alg((size_t)(NN + 1) * 4);
    int* cursor = (int*)w;      w += alg((size_t)NN * 4);
    int* csr = (int*)w;         w += alg((size_t)NE * 4);
    float* dinv = (float*)w;    w += alg((size_t)NN * 4);
    int* bsum = (int*)w;        w += alg((size_t)SCB * 4);
    int* bpre = (int*)w;        w += alg((size_t)SCB * 4);
    float* stats = (float*)w;   w += alg(256 * 4);
    float* ss = (float*)w;      w += alg(256 * 4);
    float* A = (float*)w;       w += alg((size_t)NN * HD * 4);
    float* T = (float*)w;       w += alg((size_t)NN * HD * 4);

    const int* src = ei;
    const int* dst = ei + NE;

    hipMemsetAsync(counts, 0, (size_t)NN * 4, stream);
    k_count<<<(NE + 255) / 256, 256, 0, stream>>>(dst, counts);
    k_bsum<<<SCB, 256, 0, stream>>>(counts, bsum);
    k_bscan<<<1, 256, 0, stream>>>(bsum, bpre);
    k_offsets<<<SCB, 256, 0, stream>>>(counts, bpre, offsets, cursor, dinv);
    k_fill<<<(NE + 255) / 256, 256, 0, stream>>>(src, dst, cursor, csr);

    const float* hin = x;
    for (int L = 0; L < 3; ++L) {
        k_gemm<<<(NN + 63) / 64, 256, 0, stream>>>(hin, W[L], T, ss, L > 0);
        hipMemsetAsync(stats, 0, 256 * 4, stream);
        k_aggregate<<<(NN + 1) / 2, 256, 0, stream>>>(T, offsets, csr, dinv, bb[L], A);
        k_colstats<<<256, 256, 0, stream>>>(A, stats);
        k_bnfinal<<<1, 128, 0, stream>>>(stats, gg[L], be[L], ss);
        hin = A;
    }

    k_poolmlp<<<BG, 128, 0, stream>>>(A, batch, ss, gf, M1w, M1b, M2w, M2b, M3w, M3b, out);
}

// Round 3
// 535.368 us; speedup vs baseline: 1.7371x; 1.3535x over previous
//
#include <hip/hip_runtime.h>

#define NN 50000
#define NE 800000
#define BG 512
#define HD 128
#define GD 32
#define MD 128
#define EPSV 1e-5f
#define SCB 196  // ceil(NN/256) scan blocks

// bf16 helpers (RNE pack, cheap unpack)
static __device__ __forceinline__ unsigned short f2bf(float f) {
    unsigned int u = __float_as_uint(f);
    u += 0x7fffu + ((u >> 16) & 1u);
    return (unsigned short)(u >> 16);
}
static __device__ __forceinline__ float bf_lo(unsigned int v) {
    return __uint_as_float(v << 16);
}
static __device__ __forceinline__ float bf_hi(unsigned int v) {
    return __uint_as_float(v & 0xffff0000u);
}

// ---------------- CSR build ----------------
__global__ void k_count(const int* __restrict__ dst, int* __restrict__ counts) {
    int e = blockIdx.x * blockDim.x + threadIdx.x;
    if (e < NE) atomicAdd(&counts[dst[e]], 1);
}

__global__ __launch_bounds__(256) void k_bsum(const int* __restrict__ counts,
                                              int* __restrict__ bsum) {
    __shared__ int ls[256];
    int i = blockIdx.x * 256 + threadIdx.x;
    ls[threadIdx.x] = (i < NN) ? counts[i] : 0;
    __syncthreads();
    for (int off = 128; off; off >>= 1) {
        if (threadIdx.x < off) ls[threadIdx.x] += ls[threadIdx.x + off];
        __syncthreads();
    }
    if (threadIdx.x == 0) bsum[blockIdx.x] = ls[0];
}

__global__ __launch_bounds__(256) void k_bscan(const int* __restrict__ bsum,
                                               int* __restrict__ bpre) {
    __shared__ int ls[256];
    int t = threadIdx.x;
    int v = (t < SCB) ? bsum[t] : 0;
    ls[t] = v;
    __syncthreads();
    for (int off = 1; off < 256; off <<= 1) {
        int cur = ls[t];
        int add = (t >= off) ? ls[t - off] : 0;
        __syncthreads();
        ls[t] = cur + add;
        __syncthreads();
    }
    if (t < SCB) bpre[t] = ls[t] - v;  // exclusive
}

__global__ __launch_bounds__(256) void k_offsets(const int* __restrict__ counts,
                                                 const int* __restrict__ bpre,
                                                 int* __restrict__ offsets,
                                                 int* __restrict__ cursor,
                                                 float* __restrict__ dinv) {
    __shared__ int ls[256];
    int t = threadIdx.x;
    int i = blockIdx.x * 256 + t;
    int c = (i < NN) ? counts[i] : 0;
    ls[t] = c;
    __syncthreads();
    for (int off = 1; off < 256; off <<= 1) {
        int cur = ls[t];
        int add = (t >= off) ? ls[t - off] : 0;
        __syncthreads();
        ls[t] = cur + add;
        __syncthreads();
    }
    if (i < NN) {
        int excl = ls[t] - c + bpre[blockIdx.x];
        offsets[i] = excl;
        cursor[i] = excl;
        dinv[i] = rsqrtf((float)(c + 1));  // in-degree + self loop
        if (i == NN - 1) offsets[NN] = NE;
    }
}

__global__ void k_fill(const int* __restrict__ src, const int* __restrict__ dst,
                       int* __restrict__ cursor, int* __restrict__ csr) {
    int e = blockIdx.x * blockDim.x + threadIdx.x;
    if (e < NE) {
        int d = dst[e];
        int p = atomicAdd(&cursor[d], 1);
        csr[p] = src[e];
    }
}

// ---------------- GEMM: T(bf16) = BNReLU?(In) @ W ----------------
__global__ __launch_bounds__(256) void k_gemm(const float* __restrict__ In,
                                              const float* __restrict__ W,
                                              unsigned short* __restrict__ Th,
                                              const float* __restrict__ ss,
                                              int useBN) {
    __shared__ float As[32][64];   // transposed: [k][row]
    __shared__ float Ws[32][128];  // [k][col]
    int tid = threadIdx.x;
    int rowBase = blockIdx.x * 64;
    int r0 = (tid >> 5) * 8;
    int c0 = (tid & 31) * 4;
    float acc[8][4];
#pragma unroll
    for (int i = 0; i < 8; ++i)
#pragma unroll
        for (int j = 0; j < 4; ++j) acc[i][j] = 0.f;

    for (int k0 = 0; k0 < HD; k0 += 32) {
#pragma unroll
        for (int t = 0; t < 2; ++t) {
            int q = tid + t * 256;
            int row = q & 63;
            int kq = q >> 6;
            int rg = rowBase + row;
            if (rg >= NN) rg = NN - 1;
            int col = k0 + kq * 4;
            float4 v = *(const float4*)&In[(size_t)rg * HD + col];
            if (useBN) {
                float4 s = *(const float4*)&ss[col];
                float4 h = *(const float4*)&ss[128 + col];
                v.x = fmaxf(v.x * s.x + h.x, 0.f);
                v.y = fmaxf(v.y * s.y + h.y, 0.f);
                v.z = fmaxf(v.z * s.z + h.z, 0.f);
                v.w = fmaxf(v.w * s.w + h.w, 0.f);
            }
            As[col - k0 + 0][row] = v.x;
            As[col - k0 + 1][row] = v.y;
            As[col - k0 + 2][row] = v.z;
            As[col - k0 + 3][row] = v.w;
        }
#pragma unroll
        for (int t = 0; t < 4; ++t) {
            int q = tid + t * 256;
            int kk = q >> 5;
            int c4 = (q & 31) * 4;
            *(float4*)&Ws[kk][c4] = *(const float4*)&W[(size_t)(k0 + kk) * HD + c4];
        }
        __syncthreads();
#pragma unroll
        for (int kk = 0; kk < 32; ++kk) {
            float4 a0 = *(const float4*)&As[kk][r0];
            float4 a1 = *(const float4*)&As[kk][r0 + 4];
            float4 w = *(const float4*)&Ws[kk][c0];
            float av[8] = {a0.x, a0.y, a0.z, a0.w, a1.x, a1.y, a1.z, a1.w};
            float wv[4] = {w.x, w.y, w.z, w.w};
#pragma unroll
            for (int i = 0; i < 8; ++i)
#pragma unroll
                for (int j = 0; j < 4; ++j) acc[i][j] += av[i] * wv[j];
        }
        __syncthreads();
    }
#pragma unroll
    for (int i = 0; i < 8; ++i) {
        int row = rowBase + r0 + i;
        if (row < NN) {
            ushort4 o;
            o.x = f2bf(acc[i][0]);
            o.y = f2bf(acc[i][1]);
            o.z = f2bf(acc[i][2]);
            o.w = f2bf(acc[i][3]);
            *(ushort4*)&Th[(size_t)row * HD + c0] = o;
        }
    }
}

// ---------------- Aggregate: A[d] = dinv[d]*sum dinv[s]*T[s] + dinv[d]^2*T[d] + b ----------------
// One 64-lane wave per dst row; lane l covers features 2l, 2l+1 (one 4B packed load).
// 4-edge unroll for memory-level parallelism against L2-miss latency.
__global__ __launch_bounds__(256) void k_aggregate(const unsigned int* __restrict__ Tu,
                                                   const int* __restrict__ offsets,
                                                   const int* __restrict__ csr,
                                                   const float* __restrict__ dinv,
                                                   const float* __restrict__ bias,
                                                   float* __restrict__ A) {
    int d = blockIdx.x * 4 + (threadIdx.x >> 6);
    int l = threadIdx.x & 63;
    if (d >= NN) return;
    int start = offsets[d], end = offsets[d + 1];
    float a0 = 0.f, a1 = 0.f;
    int j = start;
    for (; j + 3 < end; j += 4) {
        int s0 = csr[j], s1 = csr[j + 1], s2 = csr[j + 2], s3 = csr[j + 3];
        unsigned int v0 = Tu[(size_t)s0 * 64 + l];
        unsigned int v1 = Tu[(size_t)s1 * 64 + l];
        unsigned int v2 = Tu[(size_t)s2 * 64 + l];
        unsigned int v3 = Tu[(size_t)s3 * 64 + l];
        float w0 = dinv[s0], w1 = dinv[s1], w2 = dinv[s2], w3 = dinv[s3];
        a0 += w0 * bf_lo(v0); a1 += w0 * bf_hi(v0);
        a0 += w1 * bf_lo(v1); a1 += w1 * bf_hi(v1);
        a0 += w2 * bf_lo(v2); a1 += w2 * bf_hi(v2);
        a0 += w3 * bf_lo(v3); a1 += w3 * bf_hi(v3);
    }
    for (; j < end; ++j) {
        int s0 = csr[j];
        unsigned int v0 = Tu[(size_t)s0 * 64 + l];
        float w0 = dinv[s0];
        a0 += w0 * bf_lo(v0);
        a1 += w0 * bf_hi(v0);
    }
    float di = dinv[d];
    unsigned int vd = Tu[(size_t)d * 64 + l];
    float2 bs = *(const float2*)&bias[2 * l];
    float2 o;
    o.x = di * a0 + di * di * bf_lo(vd) + bs.x;
    o.y = di * a1 + di * di * bf_hi(vd) + bs.y;
    *(float2*)&A[(size_t)d * HD + 2 * l] = o;
}

// ---------------- BN stats: column sum & sumsq over raw A ----------------
__global__ __launch_bounds__(256) void k_colstats(const float* __restrict__ A,
                                                  float* __restrict__ stats) {
    int f = threadIdx.x & 127;
    int half = threadIdx.x >> 7;
    float s = 0.f, sq = 0.f;
    for (int row = blockIdx.x * 2 + half; row < NN; row += gridDim.x * 2) {
        float v = A[(size_t)row * HD + f];
        s += v;
        sq += v * v;
    }
    __shared__ float ls[256], lq[256];
    ls[threadIdx.x] = s;
    lq[threadIdx.x] = sq;
    __syncthreads();
    if (half == 0) {
        atomicAdd(&stats[f], ls[f] + ls[f + 128]);
        atomicAdd(&stats[128 + f], lq[f] + lq[f + 128]);
    }
}

__global__ void k_bnfinal(const float* __restrict__ stats, const float* __restrict__ gamma,
                          const float* __restrict__ beta, float* __restrict__ ss) {
    int c = threadIdx.x;
    if (c < HD) {
        float mu = stats[c] * (1.f / NN);
        float var = stats[128 + c] * (1.f / NN) - mu * mu;
        float sc = gamma[c] * rsqrtf(var + EPSV);
        ss[c] = sc;
        ss[128 + c] = beta[c] - mu * sc;
    }
}

// ---------------- Fused pool (+BN of layer 2) + MLP head ----------------
__global__ __launch_bounds__(128) void k_poolmlp(const float* __restrict__ A,
                                                 const int* __restrict__ batch,
                                                 const float* __restrict__ ss,
                                                 const float* __restrict__ gfeat,
                                                 const float* __restrict__ M1w,
                                                 const float* __restrict__ M1b,
                                                 const float* __restrict__ M2w,
                                                 const float* __restrict__ M2b,
                                                 const float* __restrict__ M3w,
                                                 const float* __restrict__ M3b,
                                                 float* __restrict__ out) {
    __shared__ int sb[2];
    __shared__ float z[HD + GD];
    __shared__ float z1[MD];
    __shared__ float z2[MD / 2];
    int b = blockIdx.x, t = threadIdx.x;
    if (t < 2) {
        int val = b + t;
        int lo = 0, hi = NN;
        while (lo < hi) {
            int mid = (lo + hi) >> 1;
            if (batch[mid] < val) lo = mid + 1; else hi = mid;
        }
        sb[t] = lo;
    }
    __syncthreads();
    int start = sb[0], end = sb[1];
    float s = ss[t], h = ss[128 + t];
    float acc = 0.f;
    for (int r = start; r < end; ++r)
        acc += fmaxf(A[(size_t)r * HD + t] * s + h, 0.f);
    float ic = 1.f / fmaxf((float)(end - start), 1.f);
    z[t] = acc * ic;
    if (t < GD) z[HD + t] = gfeat[b * GD + t];
    __syncthreads();
    float a = M1b[t];
    for (int k = 0; k < HD + GD; ++k) a += z[k] * M1w[k * MD + t];
    z1[t] = fmaxf(a, 0.f);
    __syncthreads();
    if (t < MD / 2) {
        float a2 = M2b[t];
        for (int k = 0; k < MD; ++k) a2 += z1[k] * M2w[k * (MD / 2) + t];
        z2[t] = fmaxf(a2, 0.f);
    }
    __syncthreads();
    if (t < 64) {
        float p = z2[t] * M3w[t];
#pragma unroll
        for (int off = 32; off; off >>= 1) p += __shfl_down(p, off);
        if (t == 0) out[b] = p + M3b[0];
    }
}

static inline size_t alg(size_t x) { return (x + 255) & ~(size_t)255; }

extern "C" void kernel_launch(void* const* d_in, const int* in_sizes, int n_in,
                              void* d_out, int out_size, void* d_ws, size_t ws_size,
                              hipStream_t stream) {
    const float* x = (const float*)d_in[0];
    const int* ei = (const int*)d_in[1];
    const int* batch = (const int*)d_in[2];
    const float* gf = (const float*)d_in[3];
    const float* W[3] = {(const float*)d_in[4], (const float*)d_in[8], (const float*)d_in[12]};
    const float* bb[3] = {(const float*)d_in[5], (const float*)d_in[9], (const float*)d_in[13]};
    const float* gg[3] = {(const float*)d_in[6], (const float*)d_in[10], (const float*)d_in[14]};
    const float* be[3] = {(const float*)d_in[7], (const float*)d_in[11], (const float*)d_in[15]};
    const float* M1w = (const float*)d_in[16];
    const float* M1b = (const float*)d_in[17];
    const float* M2w = (const float*)d_in[18];
    const float* M2b = (const float*)d_in[19];
    const float* M3w = (const float*)d_in[20];
    const float* M3b = (const float*)d_in[21];
    float* out = (float*)d_out;

    char* w = (char*)d_ws;
    int* counts = (int*)w;      w += alg((size_t)NN * 4);
    int* offsets = (int*)w;     w += alg((size_t)(NN + 1) * 4);
    int* cursor = (int*)w;      w += alg((size_t)NN * 4);
    int* csr = (int*)w;         w += alg((size_t)NE * 4);
    float* dinv = (float*)w;    w += alg((size_t)NN * 4);
    int* bsum = (int*)w;        w += alg((size_t)SCB * 4);
    int* bpre = (int*)w;        w += alg((size_t)SCB * 4);
    float* stats = (float*)w;   w += alg(256 * 4);
    float* ss = (float*)w;      w += alg(256 * 4);
    float* A = (float*)w;       w += alg((size_t)NN * HD * 4);
    unsigned short* Th = (unsigned short*)w;  w += alg((size_t)NN * HD * 2);

    const int* src = ei;
    const int* dst = ei + NE;

    hipMemsetAsync(counts, 0, (size_t)NN * 4, stream);
    k_count<<<(NE + 255) / 256, 256, 0, stream>>>(dst, counts);
    k_bsum<<<SCB, 256, 0, stream>>>(counts, bsum);
    k_bscan<<<1, 256, 0, stream>>>(bsum, bpre);
    k_offsets<<<SCB, 256, 0, stream>>>(counts, bpre, offsets, cursor, dinv);
    k_fill<<<(NE + 255) / 256, 256, 0, stream>>>(src, dst, cursor, csr);

    const float* hin = x;
    for (int L = 0; L < 3; ++L) {
        k_gemm<<<(NN + 63) / 64, 256, 0, stream>>>(hin, W[L], Th, ss, L > 0);
        hipMemsetAsync(stats, 0, 256 * 4, stream);
        k_aggregate<<<(NN + 3) / 4, 256, 0, stream>>>((const unsigned int*)Th, offsets, csr,
                                                      dinv, bb[L], A);
        k_colstats<<<512, 256, 0, stream>>>(A, stats);
        k_bnfinal<<<1, 128, 0, stream>>>(stats, gg[L], be[L], ss);
        hin = A;
    }

    k_poolmlp<<<BG, 128, 0, stream>>>(A, batch, ss, gf, M1w, M1b, M2w, M2b, M3w, M3b, out);
}

// Round 4
// 473.409 us; speedup vs baseline: 1.9644x; 1.1309x over previous
//
#include <hip/hip_runtime.h>

#define NN 50000
#define NE 800000
#define BG 512
#define HD 128
#define GD 32
#define MD 128
#define EPSV 1e-5f
#define SCB 196   // ceil(NN/256) scan blocks
#define NBK 256   // dst buckets
#define BSTR 196  // dst per bucket (196*256 >= NN)
#define BCAP 4096 // edge capacity per bucket (mean 3136, sd ~56)
#define SP 136    // LDS row stride (shorts) for gemm tiles

typedef __attribute__((ext_vector_type(8))) short bf16x8;
typedef __attribute__((ext_vector_type(4))) float f32x4;

// bf16 helpers (RNE pack, cheap unpack)
static __device__ __forceinline__ unsigned short f2bf(float f) {
    unsigned int u = __float_as_uint(f);
    u += 0x7fffu + ((u >> 16) & 1u);
    return (unsigned short)(u >> 16);
}
static __device__ __forceinline__ float bf_lo(unsigned int v) {
    return __uint_as_float(v << 16);
}
static __device__ __forceinline__ float bf_hi(unsigned int v) {
    return __uint_as_float(v & 0xffff0000u);
}

// ---------------- Pass 1: count dst degrees + bin edges by dst bucket ----------------
// 2048 edges/block. LDS histogram -> one global atomic per (block,bucket) ->
// contiguous block-exclusive slot runs (no cross-XCD line bouncing).
__global__ __launch_bounds__(256) void k_bin(const int* __restrict__ src,
                                             const int* __restrict__ dst,
                                             int* __restrict__ counts,
                                             int* __restrict__ bucket_cnt,
                                             int2* __restrict__ binned) {
    __shared__ int hcnt[NBK];
    __shared__ int hbase[NBK];
    int tid = threadIdx.x;
    int e0 = blockIdx.x * 2048;
    int s[8], d[8], bk[8], rk[8];
#pragma unroll
    for (int i = 0; i < 8; ++i) {
        int e = e0 + i * 256 + tid;
        if (e < NE) {
            s[i] = src[e];
            d[i] = dst[e];
            bk[i] = d[i] / BSTR;
            atomicAdd(&counts[d[i]], 1);
        } else {
            bk[i] = -1;
        }
    }
    hcnt[tid] = 0;
    __syncthreads();
#pragma unroll
    for (int i = 0; i < 8; ++i)
        if (bk[i] >= 0) rk[i] = atomicAdd(&hcnt[bk[i]], 1);
    __syncthreads();
    hbase[tid] = atomicAdd(&bucket_cnt[tid], hcnt[tid]);
    __syncthreads();
#pragma unroll
    for (int i = 0; i < 8; ++i)
        if (bk[i] >= 0)
            binned[(size_t)bk[i] * BCAP + hbase[bk[i]] + rk[i]] = make_int2(s[i], d[i]);
}

// ---------------- scan: counts -> offsets/cursor/dinv ----------------
__global__ __launch_bounds__(256) void k_bsum(const int* __restrict__ counts,
                                              int* __restrict__ bsum) {
    __shared__ int ls[256];
    int i = blockIdx.x * 256 + threadIdx.x;
    ls[threadIdx.x] = (i < NN) ? counts[i] : 0;
    __syncthreads();
    for (int off = 128; off; off >>= 1) {
        if (threadIdx.x < off) ls[threadIdx.x] += ls[threadIdx.x + off];
        __syncthreads();
    }
    if (threadIdx.x == 0) bsum[blockIdx.x] = ls[0];
}

__global__ __launch_bounds__(256) void k_bscan(const int* __restrict__ bsum,
                                               int* __restrict__ bpre) {
    __shared__ int ls[256];
    int t = threadIdx.x;
    int v = (t < SCB) ? bsum[t] : 0;
    ls[t] = v;
    __syncthreads();
    for (int off = 1; off < 256; off <<= 1) {
        int cur = ls[t];
        int add = (t >= off) ? ls[t - off] : 0;
        __syncthreads();
        ls[t] = cur + add;
        __syncthreads();
    }
    if (t < SCB) bpre[t] = ls[t] - v;  // exclusive
}

__global__ __launch_bounds__(256) void k_offsets(const int* __restrict__ counts,
                                                 const int* __restrict__ bpre,
                                                 int* __restrict__ offsets,
                                                 int* __restrict__ cursor,
                                                 float* __restrict__ dinv) {
    __shared__ int ls[256];
    int t = threadIdx.x;
    int i = blockIdx.x * 256 + t;
    int c = (i < NN) ? counts[i] : 0;
    ls[t] = c;
    __syncthreads();
    for (int off = 1; off < 256; off <<= 1) {
        int cur = ls[t];
        int add = (t >= off) ? ls[t - off] : 0;
        __syncthreads();
        ls[t] = cur + add;
        __syncthreads();
    }
    if (i < NN) {
        int excl = ls[t] - c + bpre[blockIdx.x];
        offsets[i] = excl;
        cursor[i] = excl;
        dinv[i] = rsqrtf((float)(c + 1));  // in-degree + self loop
        if (i == NN - 1) offsets[NN] = NE;
    }
}

// ---------------- Pass 2: bucket-local CSR fill ----------------
// One block per bucket: its cursor slice (~784B) and csr region (~12.5KB) are
// block-exclusive -> each cache line dirtied by exactly one XCD, written once.
__global__ __launch_bounds__(256) void k_fill2(const int2* __restrict__ binned,
                                               const int* __restrict__ bucket_cnt,
                                               int* __restrict__ cursor,
                                               int* __restrict__ csr) {
    int b = blockIdx.x;
    int nb = bucket_cnt[b];
    const int2* base = binned + (size_t)b * BCAP;
    for (int e = threadIdx.x; e < nb; e += 256) {
        int2 p = base[e];
        int pos = atomicAdd(&cursor[p.y], 1);
        csr[pos] = p.x;
    }
}

// ---------------- W pre-transpose: Wt[n][k] = bf16(W[k][n]), 3 layers ----------------
__global__ __launch_bounds__(256) void k_wtrans(const float* __restrict__ W0,
                                                const float* __restrict__ W1,
                                                const float* __restrict__ W2,
                                                unsigned short* __restrict__ Wt) {
    __shared__ unsigned short sW[128 * 130];
    const float* Wsrc = blockIdx.x == 0 ? W0 : (blockIdx.x == 1 ? W1 : W2);
#pragma unroll
    for (int i = 0; i < 64; ++i) {
        int idx = i * 256 + threadIdx.x;
        int k = idx >> 7, n = idx & 127;
        sW[n * 130 + k] = f2bf(Wsrc[idx]);
    }
    __syncthreads();
    unsigned short* o = Wt + (size_t)blockIdx.x * 16384;
#pragma unroll
    for (int i = 0; i < 64; ++i) {
        int idx = i * 256 + threadIdx.x;
        int n = idx >> 7, k = idx & 127;
        o[idx] = sW[n * 130 + k];
    }
}

// ---------------- MFMA GEMM: Th(bf16) = BNReLU?(In) @ W ----------------
// 64 rows/block, 256 thr = 4 waves x 16 rows x 128 cols. 16x16x32 bf16 MFMA.
// A-operand = Wt rows (output cols), B-operand = In rows. Verified layouts:
// A[m=lane&15][k=quad*8+j], B[k=quad*8+j][n=lane&15], D: col=lane&15 (=T row),
// row=quad*4+reg (=T col).
__global__ __launch_bounds__(256) void k_gemm(const float* __restrict__ In,
                                              const unsigned short* __restrict__ Wt,
                                              unsigned short* __restrict__ Th,
                                              const float* __restrict__ ss,
                                              int useBN) {
    __shared__ unsigned short Abf[64 * SP];
    __shared__ unsigned short WtL[128 * SP];
    int tid = threadIdx.x;
    int rowBase = blockIdx.x * 64;
    // stage In tile: f32 -> (BN+ReLU) -> bf16
#pragma unroll
    for (int i = 0; i < 8; ++i) {
        int q = tid + i * 256;   // float4 units, 0..2047
        int row = q >> 5;
        int c4 = (q & 31) * 4;
        int rg = rowBase + row;
        if (rg >= NN) rg = NN - 1;
        float4 v = *(const float4*)&In[(size_t)rg * HD + c4];
        if (useBN) {
            float4 sc = *(const float4*)&ss[c4];
            float4 sh = *(const float4*)&ss[128 + c4];
            v.x = fmaxf(v.x * sc.x + sh.x, 0.f);
            v.y = fmaxf(v.y * sc.y + sh.y, 0.f);
            v.z = fmaxf(v.z * sc.z + sh.z, 0.f);
            v.w = fmaxf(v.w * sc.w + sh.w, 0.f);
        }
        unsigned short* p = &Abf[row * SP + c4];
        p[0] = f2bf(v.x); p[1] = f2bf(v.y); p[2] = f2bf(v.z); p[3] = f2bf(v.w);
    }
    // stage Wt tile (already bf16, row-major [n][k])
#pragma unroll
    for (int i = 0; i < 8; ++i) {
        int q = tid + i * 256;   // short8 units, 0..2047
        int n = q >> 4;
        int k8 = (q & 15) * 8;
        bf16x8 w = *(const bf16x8*)&Wt[n * HD + k8];
        *(bf16x8*)&WtL[n * SP + k8] = w;
    }
    __syncthreads();
    int lane = tid & 63;
    int wv = tid >> 6;
    int quad = lane >> 4;
    int lrow = wv * 16 + (lane & 15);
    f32x4 acc[8];
#pragma unroll
    for (int c = 0; c < 8; ++c) acc[c] = (f32x4){0.f, 0.f, 0.f, 0.f};
#pragma unroll
    for (int qk = 0; qk < 4; ++qk) {
        int ko = quad * 8 + qk * 32;
        bf16x8 bfr = *(const bf16x8*)&Abf[lrow * SP + ko];
#pragma unroll
        for (int c = 0; c < 8; ++c) {
            bf16x8 afr = *(const bf16x8*)&WtL[(c * 16 + (lane & 15)) * SP + ko];
            acc[c] = __builtin_amdgcn_mfma_f32_16x16x32_bf16(afr, bfr, acc[c], 0, 0, 0);
        }
    }
    int grow = rowBase + lrow;
    if (grow < NN) {
#pragma unroll
        for (int c = 0; c < 8; ++c) {
            ushort4 o;
            o.x = f2bf(acc[c][0]);
            o.y = f2bf(acc[c][1]);
            o.z = f2bf(acc[c][2]);
            o.w = f2bf(acc[c][3]);
            *(ushort4*)&Th[(size_t)grow * HD + c * 16 + quad * 4] = o;
        }
    }
}

// ---------------- Aggregate: A[d] = dinv[d]*sum dinv[s]*T[s] + dinv[d]^2*T[d] + b ----------------
// One wave per dst row; lane l covers features 2l,2l+1. 8-edge unroll for MLP.
__global__ __launch_bounds__(256) void k_aggregate(const unsigned int* __restrict__ Tu,
                                                   const int* __restrict__ offsets,
                                                   const int* __restrict__ csr,
                                                   const float* __restrict__ dinv,
                                                   const float* __restrict__ bias,
                                                   float* __restrict__ A) {
    int d = blockIdx.x * 4 + (threadIdx.x >> 6);
    int l = threadIdx.x & 63;
    if (d >= NN) return;
    int start = offsets[d], end = offsets[d + 1];
    float a0 = 0.f, a1 = 0.f;
    int j = start;
    for (; j + 7 < end; j += 8) {
        int s[8];
        unsigned int v[8];
        float w[8];
#pragma unroll
        for (int t = 0; t < 8; ++t) s[t] = csr[j + t];
#pragma unroll
        for (int t = 0; t < 8; ++t) {
            v[t] = Tu[(size_t)s[t] * 64 + l];
            w[t] = dinv[s[t]];
        }
#pragma unroll
        for (int t = 0; t < 8; ++t) {
            a0 += w[t] * bf_lo(v[t]);
            a1 += w[t] * bf_hi(v[t]);
        }
    }
    for (; j + 3 < end; j += 4) {
        int s0 = csr[j], s1 = csr[j + 1], s2 = csr[j + 2], s3 = csr[j + 3];
        unsigned int v0 = Tu[(size_t)s0 * 64 + l];
        unsigned int v1 = Tu[(size_t)s1 * 64 + l];
        unsigned int v2 = Tu[(size_t)s2 * 64 + l];
        unsigned int v3 = Tu[(size_t)s3 * 64 + l];
        float w0 = dinv[s0], w1 = dinv[s1], w2 = dinv[s2], w3 = dinv[s3];
        a0 += w0 * bf_lo(v0); a1 += w0 * bf_hi(v0);
        a0 += w1 * bf_lo(v1); a1 += w1 * bf_hi(v1);
        a0 += w2 * bf_lo(v2); a1 += w2 * bf_hi(v2);
        a0 += w3 * bf_lo(v3); a1 += w3 * bf_hi(v3);
    }
    for (; j < end; ++j) {
        int s0 = csr[j];
        unsigned int v0 = Tu[(size_t)s0 * 64 + l];
        float w0 = dinv[s0];
        a0 += w0 * bf_lo(v0);
        a1 += w0 * bf_hi(v0);
    }
    float di = dinv[d];
    unsigned int vd = Tu[(size_t)d * 64 + l];
    float2 bs = *(const float2*)&bias[2 * l];
    float2 o;
    o.x = di * a0 + di * di * bf_lo(vd) + bs.x;
    o.y = di * a1 + di * di * bf_hi(vd) + bs.y;
    *(float2*)&A[(size_t)d * HD + 2 * l] = o;
}

// ---------------- BN stats: per-block partials (no atomics, no memset) ----------------
__global__ __launch_bounds__(256) void k_colstats(const float* __restrict__ A,
                                                  float* __restrict__ pstats) {
    int f = threadIdx.x & 127;
    int half = threadIdx.x >> 7;
    float s = 0.f, sq = 0.f;
    for (int row = blockIdx.x * 2 + half; row < NN; row += gridDim.x * 2) {
        float v = A[(size_t)row * HD + f];
        s += v;
        sq += v * v;
    }
    __shared__ float ls[256], lq[256];
    ls[threadIdx.x] = s;
    lq[threadIdx.x] = sq;
    __syncthreads();
    if (half == 0) {
        pstats[blockIdx.x * 256 + f] = ls[f] + ls[f + 128];
        pstats[blockIdx.x * 256 + 128 + f] = lq[f] + lq[f + 128];
    }
}

__global__ __launch_bounds__(256) void k_bnfinal(const float* __restrict__ pstats,
                                                 const float* __restrict__ gamma,
                                                 const float* __restrict__ beta,
                                                 float* __restrict__ ss) {
    __shared__ float sums[256];
    int t = threadIdx.x;
    float a = 0.f;
    for (int b = 0; b < 256; ++b) a += pstats[b * 256 + t];
    sums[t] = a;
    __syncthreads();
    if (t < 128) {
        float mu = sums[t] * (1.f / NN);
        float var = sums[128 + t] * (1.f / NN) - mu * mu;
        float sc = gamma[t] * rsqrtf(var + EPSV);
        ss[t] = sc;
        ss[128 + t] = beta[t] - mu * sc;
    }
}

// ---------------- Fused pool (+BN of layer 2) + MLP head ----------------
__global__ __launch_bounds__(128) void k_poolmlp(const float* __restrict__ A,
                                                 const int* __restrict__ batch,
                                                 const float* __restrict__ ss,
                                                 const float* __restrict__ gfeat,
                                                 const float* __restrict__ M1w,
                                                 const float* __restrict__ M1b,
                                                 const float* __restrict__ M2w,
                                                 const float* __restrict__ M2b,
                                                 const float* __restrict__ M3w,
                                                 const float* __restrict__ M3b,
                                                 float* __restrict__ out) {
    __shared__ int sb[2];
    __shared__ float z[HD + GD];
    __shared__ float z1[MD];
    __shared__ float z2[MD / 2];
    int b = blockIdx.x, t = threadIdx.x;
    if (t < 2) {
        int val = b + t;
        int lo = 0, hi = NN;
        while (lo < hi) {
            int mid = (lo + hi) >> 1;
            if (batch[mid] < val) lo = mid + 1; else hi = mid;
        }
        sb[t] = lo;
    }
    __syncthreads();
    int start = sb[0], end = sb[1];
    float s = ss[t], h = ss[128 + t];
    float acc = 0.f;
    for (int r = start; r < end; ++r)
        acc += fmaxf(A[(size_t)r * HD + t] * s + h, 0.f);
    float ic = 1.f / fmaxf((float)(end - start), 1.f);
    z[t] = acc * ic;
    if (t < GD) z[HD + t] = gfeat[b * GD + t];
    __syncthreads();
    float a = M1b[t];
    for (int k = 0; k < HD + GD; ++k) a += z[k] * M1w[k * MD + t];
    z1[t] = fmaxf(a, 0.f);
    __syncthreads();
    if (t < MD / 2) {
        float a2 = M2b[t];
        for (int k = 0; k < MD; ++k) a2 += z1[k] * M2w[k * (MD / 2) + t];
        z2[t] = fmaxf(a2, 0.f);
    }
    __syncthreads();
    if (t < 64) {
        float p = z2[t] * M3w[t];
#pragma unroll
        for (int off = 32; off; off >>= 1) p += __shfl_down(p, off);
        if (t == 0) out[b] = p + M3b[0];
    }
}

static inline size_t alg(size_t x) { return (x + 255) & ~(size_t)255; }

extern "C" void kernel_launch(void* const* d_in, const int* in_sizes, int n_in,
                              void* d_out, int out_size, void* d_ws, size_t ws_size,
                              hipStream_t stream) {
    const float* x = (const float*)d_in[0];
    const int* ei = (const int*)d_in[1];
    const int* batch = (const int*)d_in[2];
    const float* gf = (const float*)d_in[3];
    const float* W[3] = {(const float*)d_in[4], (const float*)d_in[8], (const float*)d_in[12]};
    const float* bb[3] = {(const float*)d_in[5], (const float*)d_in[9], (const float*)d_in[13]};
    const float* gg[3] = {(const float*)d_in[6], (const float*)d_in[10], (const float*)d_in[14]};
    const float* be[3] = {(const float*)d_in[7], (const float*)d_in[11], (const float*)d_in[15]};
    const float* M1w = (const float*)d_in[16];
    const float* M1b = (const float*)d_in[17];
    const float* M2w = (const float*)d_in[18];
    const float* M2b = (const float*)d_in[19];
    const float* M3w = (const float*)d_in[20];
    const float* M3b = (const float*)d_in[21];
    float* out = (float*)d_out;

    char* w = (char*)d_ws;
    int* counts = (int*)w;        w += alg((size_t)NN * 4);
    int* bucket_cnt = (int*)w;    w += alg((size_t)NBK * 4);
    size_t zero_span = (char*)(bucket_cnt + NBK) - (char*)counts;
    int* offsets = (int*)w;       w += alg((size_t)(NN + 1) * 4);
    int* cursor = (int*)w;        w += alg((size_t)NN * 4);
    int* csr = (int*)w;           w += alg((size_t)NE * 4);
    float* dinv = (float*)w;      w += alg((size_t)NN * 4);
    int* bsum = (int*)w;          w += alg((size_t)SCB * 4);
    int* bpre = (int*)w;          w += alg((size_t)SCB * 4);
    float* pstats = (float*)w;    w += alg((size_t)256 * 256 * 4);
    float* ss = (float*)w;        w += alg(256 * 4);
    unsigned short* Wt = (unsigned short*)w;  w += alg((size_t)3 * 16384 * 2);
    int2* binned = (int2*)w;      w += alg((size_t)NBK * BCAP * 8);
    float* A = (float*)w;         w += alg((size_t)NN * HD * 4);
    unsigned short* Th = (unsigned short*)w;  w += alg((size_t)NN * HD * 2);

    const int* src = ei;
    const int* dst = ei + NE;

    hipMemsetAsync(counts, 0, zero_span, stream);
    k_bin<<<(NE + 2047) / 2048, 256, 0, stream>>>(src, dst, counts, bucket_cnt, binned);
    k_bsum<<<SCB, 256, 0, stream>>>(counts, bsum);
    k_bscan<<<1, 256, 0, stream>>>(bsum, bpre);
    k_offsets<<<SCB, 256, 0, stream>>>(counts, bpre, offsets, cursor, dinv);
    k_fill2<<<NBK, 256, 0, stream>>>(binned, bucket_cnt, cursor, csr);
    k_wtrans<<<3, 256, 0, stream>>>(W[0], W[1], W[2], Wt);

    const float* hin = x;
    for (int L = 0; L < 3; ++L) {
        k_gemm<<<(NN + 63) / 64, 256, 0, stream>>>(hin, Wt + (size_t)L * 16384, Th, ss, L > 0);
        k_aggregate<<<(NN + 3) / 4, 256, 0, stream>>>((const unsigned int*)Th, offsets, csr,
                                                      dinv, bb[L], A);
        k_colstats<<<256, 256, 0, stream>>>(A, pstats);
        k_bnfinal<<<1, 256, 0, stream>>>(pstats, gg[L], be[L], ss);
        hin = A;
    }

    k_poolmlp<<<BG, 128, 0, stream>>>(A, batch, ss, gf, M1w, M1b, M2w, M2b, M3w, M3b, out);
}

// Round 5
// 447.966 us; speedup vs baseline: 2.0760x; 1.0568x over previous
//
#include <hip/hip_runtime.h>

#define NN 50000
#define NE 800000
#define BG 512
#define HD 128
#define GD 32
#define MD 128
#define EPSV 1e-5f
#define SCB 196   // ceil(NN/256) scan blocks
#define NBK 256   // dst buckets
#define BSTR 196  // dst per bucket (196*256 = 50176 >= NN)
#define BCAP 4096 // edge capacity per bucket (mean 3136, sd ~56)
#define SP 136    // LDS row stride (shorts) for gemm tiles

typedef __attribute__((ext_vector_type(8))) short bf16x8;
typedef __attribute__((ext_vector_type(4))) float f32x4;

// bf16 helpers (RNE pack, cheap unpack)
static __device__ __forceinline__ unsigned short f2bf(float f) {
    unsigned int u = __float_as_uint(f);
    u += 0x7fffu + ((u >> 16) & 1u);
    return (unsigned short)(u >> 16);
}
static __device__ __forceinline__ float bf_lo(unsigned int v) {
    return __uint_as_float(v << 16);
}
static __device__ __forceinline__ float bf_hi(unsigned int v) {
    return __uint_as_float(v & 0xffff0000u);
}

// ---------------- Pass 1: bin edges by dst bucket (no global per-node atomics) ----------------
// 2048 edges/block. Pack (dloc<<16)|src into 4B. LDS histogram -> one global
// atomic per (block,bucket) -> contiguous block-exclusive slot runs.
__global__ __launch_bounds__(256) void k_bin(const int* __restrict__ src,
                                             const int* __restrict__ dst,
                                             int* __restrict__ bucket_cnt,
                                             unsigned int* __restrict__ binned) {
    __shared__ int hcnt[NBK];
    __shared__ int hbase[NBK];
    int tid = threadIdx.x;
    int e0 = blockIdx.x * 2048;
    unsigned int pv[8];
    int bk[8], rk[8];
#pragma unroll
    for (int i = 0; i < 8; ++i) {
        int e = e0 + i * 256 + tid;
        if (e < NE) {
            int s = src[e];
            int d = dst[e];
            bk[i] = d / BSTR;
            pv[i] = ((unsigned int)(d - bk[i] * BSTR) << 16) | (unsigned int)s;
        } else {
            bk[i] = -1;
        }
    }
    hcnt[tid] = 0;
    __syncthreads();
#pragma unroll
    for (int i = 0; i < 8; ++i)
        if (bk[i] >= 0) rk[i] = atomicAdd(&hcnt[bk[i]], 1);
    __syncthreads();
    hbase[tid] = atomicAdd(&bucket_cnt[tid], hcnt[tid]);
    __syncthreads();
#pragma unroll
    for (int i = 0; i < 8; ++i)
        if (bk[i] >= 0)
            binned[(size_t)bk[i] * BCAP + hbase[bk[i]] + rk[i]] = pv[i];
}

// ---------------- per-bucket LDS histogram -> counts (no atomics, no memset) ----------------
__global__ __launch_bounds__(256) void k_cnt(const unsigned int* __restrict__ binned,
                                             const int* __restrict__ bucket_cnt,
                                             int* __restrict__ counts) {
    __shared__ int h[BSTR];
    int b = blockIdx.x, t = threadIdx.x;
    if (t < BSTR) h[t] = 0;
    __syncthreads();
    int nb = bucket_cnt[b];
    const unsigned int* base = binned + (size_t)b * BCAP;
    for (int e = t; e < nb; e += 256)
        atomicAdd(&h[base[e] >> 16], 1);
    __syncthreads();
    int node = b * BSTR + t;
    if (t < BSTR && node < NN) counts[node] = h[t];
}

// ---------------- scan: counts -> offsets/dinv ----------------
__global__ __launch_bounds__(256) void k_bsum(const int* __restrict__ counts,
                                              int* __restrict__ bsum) {
    __shared__ int ls[256];
    int i = blockIdx.x * 256 + threadIdx.x;
    ls[threadIdx.x] = (i < NN) ? counts[i] : 0;
    __syncthreads();
    for (int off = 128; off; off >>= 1) {
        if (threadIdx.x < off) ls[threadIdx.x] += ls[threadIdx.x + off];
        __syncthreads();
    }
    if (threadIdx.x == 0) bsum[blockIdx.x] = ls[0];
}

__global__ __launch_bounds__(256) void k_bscan(const int* __restrict__ bsum,
                                               int* __restrict__ bpre) {
    __shared__ int ls[256];
    int t = threadIdx.x;
    int v = (t < SCB) ? bsum[t] : 0;
    ls[t] = v;
    __syncthreads();
    for (int off = 1; off < 256; off <<= 1) {
        int cur = ls[t];
        int add = (t >= off) ? ls[t - off] : 0;
        __syncthreads();
        ls[t] = cur + add;
        __syncthreads();
    }
    if (t < SCB) bpre[t] = ls[t] - v;  // exclusive
}

__global__ __launch_bounds__(256) void k_offsets(const int* __restrict__ counts,
                                                 const int* __restrict__ bpre,
                                                 int* __restrict__ offsets,
                                                 float* __restrict__ dinv) {
    __shared__ int ls[256];
    int t = threadIdx.x;
    int i = blockIdx.x * 256 + t;
    int c = (i < NN) ? counts[i] : 0;
    ls[t] = c;
    __syncthreads();
    for (int off = 1; off < 256; off <<= 1) {
        int cur = ls[t];
        int add = (t >= off) ? ls[t - off] : 0;
        __syncthreads();
        ls[t] = cur + add;
        __syncthreads();
    }
    if (i < NN) {
        int excl = ls[t] - c + bpre[blockIdx.x];
        offsets[i] = excl;
        dinv[i] = rsqrtf((float)(c + 1));  // in-degree + self loop
        if (i == NN - 1) offsets[NN] = NE;
    }
}

// ---------------- Pass 2: bucket-local CSR fill via LDS cursors ----------------
// One block per bucket: cursors live in LDS; csr region is block-exclusive,
// each cache line written once by one XCD.
__global__ __launch_bounds__(256) void k_fill2(const unsigned int* __restrict__ binned,
                                               const int* __restrict__ bucket_cnt,
                                               const int* __restrict__ offsets,
                                               int* __restrict__ csr) {
    __shared__ int cur[BSTR];
    int b = blockIdx.x, t = threadIdx.x;
    int node = b * BSTR + t;
    if (t < BSTR) cur[t] = (node < NN) ? offsets[node] : 0;
    __syncthreads();
    int nb = bucket_cnt[b];
    const unsigned int* base = binned + (size_t)b * BCAP;
    for (int e = t; e < nb; e += 256) {
        unsigned int v = base[e];
        int pos = atomicAdd(&cur[v >> 16], 1);
        csr[pos] = (int)(v & 0xffffu);
    }
}

// ---------------- W pre-transpose: Wt[n][k] = bf16(W[k][n]), 3 layers ----------------
__global__ __launch_bounds__(256) void k_wtrans(const float* __restrict__ W0,
                                                const float* __restrict__ W1,
                                                const float* __restrict__ W2,
                                                unsigned short* __restrict__ Wt) {
    __shared__ unsigned short sW[128 * 130];
    const float* Wsrc = blockIdx.x == 0 ? W0 : (blockIdx.x == 1 ? W1 : W2);
#pragma unroll
    for (int i = 0; i < 64; ++i) {
        int idx = i * 256 + threadIdx.x;
        int k = idx >> 7, n = idx & 127;
        sW[n * 130 + k] = f2bf(Wsrc[idx]);
    }
    __syncthreads();
    unsigned short* o = Wt + (size_t)blockIdx.x * 16384;
#pragma unroll
    for (int i = 0; i < 64; ++i) {
        int idx = i * 256 + threadIdx.x;
        int n = idx >> 7, k = idx & 127;
        o[idx] = sW[n * 130 + k];
    }
}

// ---------------- MFMA GEMM: Th(bf16) = dinv[row] * (BNReLU?(In) @ W) ----------------
// Pre-scaled rows: aggregate's edge loop needs no per-src dinv.
__global__ __launch_bounds__(256) void k_gemm(const float* __restrict__ In,
                                              const unsigned short* __restrict__ Wt,
                                              unsigned short* __restrict__ Th,
                                              const float* __restrict__ ss,
                                              const float* __restrict__ dinv,
                                              int useBN) {
    __shared__ unsigned short Abf[64 * SP];
    __shared__ unsigned short WtL[128 * SP];
    int tid = threadIdx.x;
    int rowBase = blockIdx.x * 64;
#pragma unroll
    for (int i = 0; i < 8; ++i) {
        int q = tid + i * 256;   // float4 units, 0..2047
        int row = q >> 5;
        int c4 = (q & 31) * 4;
        int rg = rowBase + row;
        if (rg >= NN) rg = NN - 1;
        float4 v = *(const float4*)&In[(size_t)rg * HD + c4];
        if (useBN) {
            float4 sc = *(const float4*)&ss[c4];
            float4 sh = *(const float4*)&ss[128 + c4];
            v.x = fmaxf(v.x * sc.x + sh.x, 0.f);
            v.y = fmaxf(v.y * sc.y + sh.y, 0.f);
            v.z = fmaxf(v.z * sc.z + sh.z, 0.f);
            v.w = fmaxf(v.w * sc.w + sh.w, 0.f);
        }
        unsigned short* p = &Abf[row * SP + c4];
        p[0] = f2bf(v.x); p[1] = f2bf(v.y); p[2] = f2bf(v.z); p[3] = f2bf(v.w);
    }
#pragma unroll
    for (int i = 0; i < 8; ++i) {
        int q = tid + i * 256;   // short8 units, 0..2047
        int n = q >> 4;
        int k8 = (q & 15) * 8;
        bf16x8 w = *(const bf16x8*)&Wt[n * HD + k8];
        *(bf16x8*)&WtL[n * SP + k8] = w;
    }
    __syncthreads();
    int lane = tid & 63;
    int wv = tid >> 6;
    int quad = lane >> 4;
    int lrow = wv * 16 + (lane & 15);
    f32x4 acc[8];
#pragma unroll
    for (int c = 0; c < 8; ++c) acc[c] = (f32x4){0.f, 0.f, 0.f, 0.f};
#pragma unroll
    for (int qk = 0; qk < 4; ++qk) {
        int ko = quad * 8 + qk * 32;
        bf16x8 bfr = *(const bf16x8*)&Abf[lrow * SP + ko];
#pragma unroll
        for (int c = 0; c < 8; ++c) {
            bf16x8 afr = *(const bf16x8*)&WtL[(c * 16 + (lane & 15)) * SP + ko];
            acc[c] = __builtin_amdgcn_mfma_f32_16x16x32_bf16(afr, bfr, acc[c], 0, 0, 0);
        }
    }
    int grow = rowBase + lrow;
    if (grow < NN) {
        float di = dinv[grow];
#pragma unroll
        for (int c = 0; c < 8; ++c) {
            ushort4 o;
            o.x = f2bf(acc[c][0] * di);
            o.y = f2bf(acc[c][1] * di);
            o.z = f2bf(acc[c][2] * di);
            o.w = f2bf(acc[c][3] * di);
            *(ushort4*)&Th[(size_t)grow * HD + c * 16 + quad * 4] = o;
        }
    }
}

// ---------------- Aggregate: A[d] = dinv[d]*(sum Ts[s] + Ts[d]) + b ----------------
// Ts rows pre-scaled by dinv. One wave per dst row; lane l covers features
// 2l,2l+1. 8-edge unroll for memory-level parallelism.
__global__ __launch_bounds__(256) void k_aggregate(const unsigned int* __restrict__ Tu,
                                                   const int* __restrict__ offsets,
                                                   const int* __restrict__ csr,
                                                   const float* __restrict__ dinv,
                                                   const float* __restrict__ bias,
                                                   float* __restrict__ A) {
    int d = blockIdx.x * 4 + (threadIdx.x >> 6);
    int l = threadIdx.x & 63;
    if (d >= NN) return;
    int start = offsets[d], end = offsets[d + 1];
    float a0 = 0.f, a1 = 0.f;
    int j = start;
    for (; j + 7 < end; j += 8) {
        int s[8];
        unsigned int v[8];
#pragma unroll
        for (int t = 0; t < 8; ++t) s[t] = csr[j + t];
#pragma unroll
        for (int t = 0; t < 8; ++t) v[t] = Tu[(size_t)s[t] * 64 + l];
#pragma unroll
        for (int t = 0; t < 8; ++t) {
            a0 += bf_lo(v[t]);
            a1 += bf_hi(v[t]);
        }
    }
    for (; j + 3 < end; j += 4) {
        int s0 = csr[j], s1 = csr[j + 1], s2 = csr[j + 2], s3 = csr[j + 3];
        unsigned int v0 = Tu[(size_t)s0 * 64 + l];
        unsigned int v1 = Tu[(size_t)s1 * 64 + l];
        unsigned int v2 = Tu[(size_t)s2 * 64 + l];
        unsigned int v3 = Tu[(size_t)s3 * 64 + l];
        a0 += bf_lo(v0); a1 += bf_hi(v0);
        a0 += bf_lo(v1); a1 += bf_hi(v1);
        a0 += bf_lo(v2); a1 += bf_hi(v2);
        a0 += bf_lo(v3); a1 += bf_hi(v3);
    }
    for (; j < end; ++j) {
        unsigned int v0 = Tu[(size_t)csr[j] * 64 + l];
        a0 += bf_lo(v0);
        a1 += bf_hi(v0);
    }
    float di = dinv[d];
    unsigned int vd = Tu[(size_t)d * 64 + l];
    float2 bs = *(const float2*)&bias[2 * l];
    float2 o;
    o.x = di * (a0 + bf_lo(vd)) + bs.x;
    o.y = di * (a1 + bf_hi(vd)) + bs.y;
    *(float2*)&A[(size_t)d * HD + 2 * l] = o;
}

// ---------------- BN stats: per-block partials (no atomics, no memset) ----------------
__global__ __launch_bounds__(256) void k_colstats(const float* __restrict__ A,
                                                  float* __restrict__ pstats) {
    int f = threadIdx.x & 127;
    int half = threadIdx.x >> 7;
    float s = 0.f, sq = 0.f;
    for (int row = blockIdx.x * 2 + half; row < NN; row += gridDim.x * 2) {
        float v = A[(size_t)row * HD + f];
        s += v;
        sq += v * v;
    }
    __shared__ float ls[256], lq[256];
    ls[threadIdx.x] = s;
    lq[threadIdx.x] = sq;
    __syncthreads();
    if (half == 0) {
        pstats[blockIdx.x * 256 + f] = ls[f] + ls[f + 128];
        pstats[blockIdx.x * 256 + 128 + f] = lq[f] + lq[f + 128];
    }
}

__global__ __launch_bounds__(256) void k_bnfinal(const float* __restrict__ pstats,
                                                 const float* __restrict__ gamma,
                                                 const float* __restrict__ beta,
                                                 float* __restrict__ ss) {
    __shared__ float sums[256];
    int t = threadIdx.x;
    float a = 0.f;
    for (int b = 0; b < 256; ++b) a += pstats[b * 256 + t];
    sums[t] = a;
    __syncthreads();
    if (t < 128) {
        float mu = sums[t] * (1.f / NN);
        float var = sums[128 + t] * (1.f / NN) - mu * mu;
        float sc = gamma[t] * rsqrtf(var + EPSV);
        ss[t] = sc;
        ss[128 + t] = beta[t] - mu * sc;
    }
}

// ---------------- Fused pool (+BN of layer 2) + MLP head ----------------
__global__ __launch_bounds__(128) void k_poolmlp(const float* __restrict__ A,
                                                 const int* __restrict__ batch,
                                                 const float* __restrict__ ss,
                                                 const float* __restrict__ gfeat,
                                                 const float* __restrict__ M1w,
                                                 const float* __restrict__ M1b,
                                                 const float* __restrict__ M2w,
                                                 const float* __restrict__ M2b,
                                                 const float* __restrict__ M3w,
                                                 const float* __restrict__ M3b,
                                                 float* __restrict__ out) {
    __shared__ int sb[2];
    __shared__ float z[HD + GD];
    __shared__ float z1[MD];
    __shared__ float z2[MD / 2];
    int b = blockIdx.x, t = threadIdx.x;
    if (t < 2) {
        int val = b + t;
        int lo = 0, hi = NN;
        while (lo < hi) {
            int mid = (lo + hi) >> 1;
            if (batch[mid] < val) lo = mid + 1; else hi = mid;
        }
        sb[t] = lo;
    }
    __syncthreads();
    int start = sb[0], end = sb[1];
    float s = ss[t], h = ss[128 + t];
    float acc = 0.f;
    for (int r = start; r < end; ++r)
        acc += fmaxf(A[(size_t)r * HD + t] * s + h, 0.f);
    float ic = 1.f / fmaxf((float)(end - start), 1.f);
    z[t] = acc * ic;
    if (t < GD) z[HD + t] = gfeat[b * GD + t];
    __syncthreads();
    float a = M1b[t];
    for (int k = 0; k < HD + GD; ++k) a += z[k] * M1w[k * MD + t];
    z1[t] = fmaxf(a, 0.f);
    __syncthreads();
    if (t < MD / 2) {
        float a2 = M2b[t];
        for (int k = 0; k < MD; ++k) a2 += z1[k] * M2w[k * (MD / 2) + t];
        z2[t] = fmaxf(a2, 0.f);
    }
    __syncthreads();
    if (t < 64) {
        float p = z2[t] * M3w[t];
#pragma unroll
        for (int off = 32; off; off >>= 1) p += __shfl_down(p, off);
        if (t == 0) out[b] = p + M3b[0];
    }
}

static inline size_t alg(size_t x) { return (x + 255) & ~(size_t)255; }

extern "C" void kernel_launch(void* const* d_in, const int* in_sizes, int n_in,
                              void* d_out, int out_size, void* d_ws, size_t ws_size,
                              hipStream_t stream) {
    const float* x = (const float*)d_in[0];
    const int* ei = (const int*)d_in[1];
    const int* batch = (const int*)d_in[2];
    const float* gf = (const float*)d_in[3];
    const float* W[3] = {(const float*)d_in[4], (const float*)d_in[8], (const float*)d_in[12]};
    const float* bb[3] = {(const float*)d_in[5], (const float*)d_in[9], (const float*)d_in[13]};
    const float* gg[3] = {(const float*)d_in[6], (const float*)d_in[10], (const float*)d_in[14]};
    const float* be[3] = {(const float*)d_in[7], (const float*)d_in[11], (const float*)d_in[15]};
    const float* M1w = (const float*)d_in[16];
    const float* M1b = (const float*)d_in[17];
    const float* M2w = (const float*)d_in[18];
    const float* M2b = (const float*)d_in[19];
    const float* M3w = (const float*)d_in[20];
    const float* M3b = (const float*)d_in[21];
    float* out = (float*)d_out;

    char* w = (char*)d_ws;
    int* counts = (int*)w;        w += alg((size_t)NN * 4);
    int* bucket_cnt = (int*)w;    w += alg((size_t)NBK * 4);
    int* offsets = (int*)w;       w += alg((size_t)(NN + 1) * 4);
    int* csr = (int*)w;           w += alg((size_t)NE * 4);
    float* dinv = (float*)w;      w += alg((size_t)NN * 4);
    int* bsum = (int*)w;          w += alg((size_t)SCB * 4);
    int* bpre = (int*)w;          w += alg((size_t)SCB * 4);
    float* pstats = (float*)w;    w += alg((size_t)256 * 256 * 4);
    float* ss = (float*)w;        w += alg(256 * 4);
    unsigned short* Wt = (unsigned short*)w;  w += alg((size_t)3 * 16384 * 2);
    unsigned int* binned = (unsigned int*)w;  w += alg((size_t)NBK * BCAP * 4);
    float* A = (float*)w;         w += alg((size_t)NN * HD * 4);
    unsigned short* Th = (unsigned short*)w;  w += alg((size_t)NN * HD * 2);

    const int* src = ei;
    const int* dst = ei + NE;

    hipMemsetAsync(bucket_cnt, 0, (size_t)NBK * 4, stream);
    k_bin<<<(NE + 2047) / 2048, 256, 0, stream>>>(src, dst, bucket_cnt, binned);
    k_cnt<<<NBK, 256, 0, stream>>>(binned, bucket_cnt, counts);
    k_bsum<<<SCB, 256, 0, stream>>>(counts, bsum);
    k_bscan<<<1, 256, 0, stream>>>(bsum, bpre);
    k_offsets<<<SCB, 256, 0, stream>>>(counts, bpre, offsets, dinv);
    k_fill2<<<NBK, 256, 0, stream>>>(binned, bucket_cnt, offsets, csr);
    k_wtrans<<<3, 256, 0, stream>>>(W[0], W[1], W[2], Wt);

    const float* hin = x;
    for (int L = 0; L < 3; ++L) {
        k_gemm<<<(NN + 63) / 64, 256, 0, stream>>>(hin, Wt + (size_t)L * 16384, Th, ss,
                                                   dinv, L > 0);
        k_aggregate<<<(NN + 3) / 4, 256, 0, stream>>>((const unsigned int*)Th, offsets, csr,
                                                      dinv, bb[L], A);
        k_colstats<<<256, 256, 0, stream>>>(A, pstats);
        k_bnfinal<<<1, 256, 0, stream>>>(pstats, gg[L], be[L], ss);
        hin = A;
    }

    k_poolmlp<<<BG, 128, 0, stream>>>(A, batch, ss, gf, M1w, M1b, M2w, M2b, M3w, M3b, out);
}

// Round 6
// 443.022 us; speedup vs baseline: 2.0992x; 1.0112x over previous
//
#include <hip/hip_runtime.h>

#define NN 50000
#define NE 800000
#define BG 512
#define HD 128
#define GD 32
#define MD 128
#define EPSV 1e-5f
#define SCB 196   // ceil(NN/256) scan blocks
#define NBK 256   // dst buckets
#define BSTR 196  // dst per bucket (196*256 = 50176 >= NN)
#define BCAP 4096 // edge capacity per bucket (mean 3136, sd ~56)
#define SP 136    // LDS row stride (shorts) for gemm tiles

typedef __attribute__((ext_vector_type(8))) short bf16x8;
typedef __attribute__((ext_vector_type(4))) float f32x4;

// bf16 helpers (RNE pack, cheap unpack)
static __device__ __forceinline__ unsigned short f2bf(float f) {
    unsigned int u = __float_as_uint(f);
    u += 0x7fffu + ((u >> 16) & 1u);
    return (unsigned short)(u >> 16);
}
static __device__ __forceinline__ float bf_lo(unsigned int v) {
    return __uint_as_float(v << 16);
}
static __device__ __forceinline__ float bf_hi(unsigned int v) {
    return __uint_as_float(v & 0xffff0000u);
}

// ---------------- Pass 1: bin edges by dst bucket (no global per-node atomics) ----------------
__global__ __launch_bounds__(256) void k_bin(const int* __restrict__ src,
                                             const int* __restrict__ dst,
                                             int* __restrict__ bucket_cnt,
                                             unsigned int* __restrict__ binned) {
    __shared__ int hcnt[NBK];
    __shared__ int hbase[NBK];
    int tid = threadIdx.x;
    int e0 = blockIdx.x * 2048;
    unsigned int pv[8];
    int bk[8], rk[8];
#pragma unroll
    for (int i = 0; i < 8; ++i) {
        int e = e0 + i * 256 + tid;
        if (e < NE) {
            int s = src[e];
            int d = dst[e];
            bk[i] = d / BSTR;
            pv[i] = ((unsigned int)(d - bk[i] * BSTR) << 16) | (unsigned int)s;
        } else {
            bk[i] = -1;
        }
    }
    hcnt[tid] = 0;
    __syncthreads();
#pragma unroll
    for (int i = 0; i < 8; ++i)
        if (bk[i] >= 0) rk[i] = atomicAdd(&hcnt[bk[i]], 1);
    __syncthreads();
    hbase[tid] = atomicAdd(&bucket_cnt[tid], hcnt[tid]);
    __syncthreads();
#pragma unroll
    for (int i = 0; i < 8; ++i)
        if (bk[i] >= 0)
            binned[(size_t)bk[i] * BCAP + hbase[bk[i]] + rk[i]] = pv[i];
}

// ---------------- per-bucket LDS histogram -> counts ----------------
__global__ __launch_bounds__(256) void k_cnt(const unsigned int* __restrict__ binned,
                                             const int* __restrict__ bucket_cnt,
                                             int* __restrict__ counts) {
    __shared__ int h[BSTR];
    int b = blockIdx.x, t = threadIdx.x;
    if (t < BSTR) h[t] = 0;
    __syncthreads();
    int nb = bucket_cnt[b];
    const unsigned int* base = binned + (size_t)b * BCAP;
    for (int e = t; e < nb; e += 256)
        atomicAdd(&h[base[e] >> 16], 1);
    __syncthreads();
    int node = b * BSTR + t;
    if (t < BSTR && node < NN) counts[node] = h[t];
}

// ---------------- scan: counts -> offsets/dinv ----------------
__global__ __launch_bounds__(256) void k_bsum(const int* __restrict__ counts,
                                              int* __restrict__ bsum) {
    __shared__ int ls[256];
    int i = blockIdx.x * 256 + threadIdx.x;
    ls[threadIdx.x] = (i < NN) ? counts[i] : 0;
    __syncthreads();
    for (int off = 128; off; off >>= 1) {
        if (threadIdx.x < off) ls[threadIdx.x] += ls[threadIdx.x + off];
        __syncthreads();
    }
    if (threadIdx.x == 0) bsum[blockIdx.x] = ls[0];
}

__global__ __launch_bounds__(256) void k_bscan(const int* __restrict__ bsum,
                                               int* __restrict__ bpre) {
    __shared__ int ls[256];
    int t = threadIdx.x;
    int v = (t < SCB) ? bsum[t] : 0;
    ls[t] = v;
    __syncthreads();
    for (int off = 1; off < 256; off <<= 1) {
        int cur = ls[t];
        int add = (t >= off) ? ls[t - off] : 0;
        __syncthreads();
        ls[t] = cur + add;
        __syncthreads();
    }
    if (t < SCB) bpre[t] = ls[t] - v;  // exclusive
}

__global__ __launch_bounds__(256) void k_offsets(const int* __restrict__ counts,
                                                 const int* __restrict__ bpre,
                                                 int* __restrict__ offsets,
                                                 float* __restrict__ dinv) {
    __shared__ int ls[256];
    int t = threadIdx.x;
    int i = blockIdx.x * 256 + t;
    int c = (i < NN) ? counts[i] : 0;
    ls[t] = c;
    __syncthreads();
    for (int off = 1; off < 256; off <<= 1) {
        int cur = ls[t];
        int add = (t >= off) ? ls[t - off] : 0;
        __syncthreads();
        ls[t] = cur + add;
        __syncthreads();
    }
    if (i < NN) {
        int excl = ls[t] - c + bpre[blockIdx.x];
        offsets[i] = excl;
        dinv[i] = rsqrtf((float)(c + 1));  // in-degree + self loop
        if (i == NN - 1) offsets[NN] = NE;
    }
}

// ---------------- Pass 2: bucket-local CSR fill via LDS cursors ----------------
__global__ __launch_bounds__(256) void k_fill2(const unsigned int* __restrict__ binned,
                                               const int* __restrict__ bucket_cnt,
                                               const int* __restrict__ offsets,
                                               int* __restrict__ csr) {
    __shared__ int cur[BSTR];
    int b = blockIdx.x, t = threadIdx.x;
    int node = b * BSTR + t;
    if (t < BSTR) cur[t] = (node < NN) ? offsets[node] : 0;
    __syncthreads();
    int nb = bucket_cnt[b];
    const unsigned int* base = binned + (size_t)b * BCAP;
    for (int e = t; e < nb; e += 256) {
        unsigned int v = base[e];
        int pos = atomicAdd(&cur[v >> 16], 1);
        csr[pos] = (int)(v & 0xffffu);
    }
}

// ---------------- W pre-transpose: Wt[n][k] = bf16(W[k][n]), 3 layers ----------------
__global__ __launch_bounds__(256) void k_wtrans(const float* __restrict__ W0,
                                                const float* __restrict__ W1,
                                                const float* __restrict__ W2,
                                                unsigned short* __restrict__ Wt) {
    __shared__ unsigned short sW[128 * 130];
    const float* Wsrc = blockIdx.x == 0 ? W0 : (blockIdx.x == 1 ? W1 : W2);
#pragma unroll
    for (int i = 0; i < 64; ++i) {
        int idx = i * 256 + threadIdx.x;
        int k = idx >> 7, n = idx & 127;
        sW[n * 130 + k] = f2bf(Wsrc[idx]);
    }
    __syncthreads();
    unsigned short* o = Wt + (size_t)blockIdx.x * 16384;
#pragma unroll
    for (int i = 0; i < 64; ++i) {
        int idx = i * 256 + threadIdx.x;
        int n = idx >> 7, k = idx & 127;
        o[idx] = sW[n * 130 + k];
    }
}

// ---------------- MFMA GEMM: Th(bf16) = dinv[row] * (BNReLU?(In) @ W) ----------------
__global__ __launch_bounds__(256) void k_gemm(const float* __restrict__ In,
                                              const unsigned short* __restrict__ Wt,
                                              unsigned short* __restrict__ Th,
                                              const float* __restrict__ ss,
                                              const float* __restrict__ dinv,
                                              int useBN) {
    __shared__ unsigned short Abf[64 * SP];
    __shared__ unsigned short WtL[128 * SP];
    int tid = threadIdx.x;
    int rowBase = blockIdx.x * 64;
#pragma unroll
    for (int i = 0; i < 8; ++i) {
        int q = tid + i * 256;   // float4 units, 0..2047
        int row = q >> 5;
        int c4 = (q & 31) * 4;
        int rg = rowBase + row;
        if (rg >= NN) rg = NN - 1;
        float4 v = *(const float4*)&In[(size_t)rg * HD + c4];
        if (useBN) {
            float4 sc = *(const float4*)&ss[c4];
            float4 sh = *(const float4*)&ss[128 + c4];
            v.x = fmaxf(v.x * sc.x + sh.x, 0.f);
            v.y = fmaxf(v.y * sc.y + sh.y, 0.f);
            v.z = fmaxf(v.z * sc.z + sh.z, 0.f);
            v.w = fmaxf(v.w * sc.w + sh.w, 0.f);
        }
        unsigned short* p = &Abf[row * SP + c4];
        p[0] = f2bf(v.x); p[1] = f2bf(v.y); p[2] = f2bf(v.z); p[3] = f2bf(v.w);
    }
#pragma unroll
    for (int i = 0; i < 8; ++i) {
        int q = tid + i * 256;   // short8 units, 0..2047
        int n = q >> 4;
        int k8 = (q & 15) * 8;
        bf16x8 w = *(const bf16x8*)&Wt[n * HD + k8];
        *(bf16x8*)&WtL[n * SP + k8] = w;
    }
    __syncthreads();
    int lane = tid & 63;
    int wv = tid >> 6;
    int quad = lane >> 4;
    int lrow = wv * 16 + (lane & 15);
    f32x4 acc[8];
#pragma unroll
    for (int c = 0; c < 8; ++c) acc[c] = (f32x4){0.f, 0.f, 0.f, 0.f};
#pragma unroll
    for (int qk = 0; qk < 4; ++qk) {
        int ko = quad * 8 + qk * 32;
        bf16x8 bfr = *(const bf16x8*)&Abf[lrow * SP + ko];
#pragma unroll
        for (int c = 0; c < 8; ++c) {
            bf16x8 afr = *(const bf16x8*)&WtL[(c * 16 + (lane & 15)) * SP + ko];
            acc[c] = __builtin_amdgcn_mfma_f32_16x16x32_bf16(afr, bfr, acc[c], 0, 0, 0);
        }
    }
    int grow = rowBase + lrow;
    if (grow < NN) {
        float di = dinv[grow];
#pragma unroll
        for (int c = 0; c < 8; ++c) {
            ushort4 o;
            o.x = f2bf(acc[c][0] * di);
            o.y = f2bf(acc[c][1] * di);
            o.z = f2bf(acc[c][2] * di);
            o.w = f2bf(acc[c][3] * di);
            *(ushort4*)&Th[(size_t)grow * HD + c * 16 + quad * 4] = o;
        }
    }
}

// ---------------- Aggregate: A[d] = dinv[d]*(sum Ts[s] + Ts[d]) + b ----------------
// One wave per dst row; lane pair-split: lanes 0-31 take edge j, lanes 32-63
// edge j+1, each lane loads uint2 (8B = features 4li..4li+3). Halves combined
// at the end via shfl_xor(32); lanes 0-31 store the float4 row.
__global__ __launch_bounds__(256) void k_aggregate(const uint2* __restrict__ T2,
                                                   const int* __restrict__ offsets,
                                                   const int* __restrict__ csr,
                                                   const float* __restrict__ dinv,
                                                   const float* __restrict__ bias,
                                                   float* __restrict__ A) {
    int d = blockIdx.x * 4 + (threadIdx.x >> 6);
    int l = threadIdx.x & 63;
    int half = l >> 5;      // which edge of the pair
    int li = l & 31;        // uint2 index within row (features 4li..4li+3)
    if (d >= NN) return;
    int start = offsets[d], end = offsets[d + 1];
    float a0 = 0.f, a1 = 0.f, a2 = 0.f, a3 = 0.f;
    int j = start;
    // 8 edges per iteration = 4 pair-steps
    for (; j + 7 < end; j += 8) {
        int s0 = csr[j + half];
        int s1 = csr[j + 2 + half];
        int s2 = csr[j + 4 + half];
        int s3 = csr[j + 6 + half];
        uint2 v0 = T2[(size_t)s0 * 32 + li];
        uint2 v1 = T2[(size_t)s1 * 32 + li];
        uint2 v2 = T2[(size_t)s2 * 32 + li];
        uint2 v3 = T2[(size_t)s3 * 32 + li];
        a0 += bf_lo(v0.x); a1 += bf_hi(v0.x); a2 += bf_lo(v0.y); a3 += bf_hi(v0.y);
        a0 += bf_lo(v1.x); a1 += bf_hi(v1.x); a2 += bf_lo(v1.y); a3 += bf_hi(v1.y);
        a0 += bf_lo(v2.x); a1 += bf_hi(v2.x); a2 += bf_lo(v2.y); a3 += bf_hi(v2.y);
        a0 += bf_lo(v3.x); a1 += bf_hi(v3.x); a2 += bf_lo(v3.y); a3 += bf_hi(v3.y);
    }
    for (; j + 1 < end; j += 2) {
        int s0 = csr[j + half];
        uint2 v0 = T2[(size_t)s0 * 32 + li];
        a0 += bf_lo(v0.x); a1 += bf_hi(v0.x); a2 += bf_lo(v0.y); a3 += bf_hi(v0.y);
    }
    if (j < end && half == 0) {
        int s0 = csr[j];
        uint2 v0 = T2[(size_t)s0 * 32 + li];
        a0 += bf_lo(v0.x); a1 += bf_hi(v0.x); a2 += bf_lo(v0.y); a3 += bf_hi(v0.y);
    }
    // combine lane halves
    a0 += __shfl_xor(a0, 32);
    a1 += __shfl_xor(a1, 32);
    a2 += __shfl_xor(a2, 32);
    a3 += __shfl_xor(a3, 32);
    if (half == 0) {
        float di = dinv[d];
        uint2 vd = T2[(size_t)d * 32 + li];
        float4 bs = *(const float4*)&bias[4 * li];
        float4 o;
        o.x = di * (a0 + bf_lo(vd.x)) + bs.x;
        o.y = di * (a1 + bf_hi(vd.x)) + bs.y;
        o.z = di * (a2 + bf_lo(vd.y)) + bs.z;
        o.w = di * (a3 + bf_hi(vd.y)) + bs.w;
        *(float4*)&A[(size_t)d * HD + 4 * li] = o;
    }
}

// ---------------- BN stats: per-block partials ----------------
__global__ __launch_bounds__(256) void k_colstats(const float* __restrict__ A,
                                                  float* __restrict__ pstats) {
    int f = threadIdx.x & 127;
    int half = threadIdx.x >> 7;
    float s = 0.f, sq = 0.f;
    for (int row = blockIdx.x * 2 + half; row < NN; row += gridDim.x * 2) {
        float v = A[(size_t)row * HD + f];
        s += v;
        sq += v * v;
    }
    __shared__ float ls[256], lq[256];
    ls[threadIdx.x] = s;
    lq[threadIdx.x] = sq;
    __syncthreads();
    if (half == 0) {
        pstats[blockIdx.x * 256 + f] = ls[f] + ls[f + 128];
        pstats[blockIdx.x * 256 + 128 + f] = lq[f] + lq[f + 128];
    }
}

__global__ __launch_bounds__(256) void k_bnfinal(const float* __restrict__ pstats,
                                                 const float* __restrict__ gamma,
                                                 const float* __restrict__ beta,
                                                 float* __restrict__ ss) {
    __shared__ float sums[256];
    int t = threadIdx.x;
    float a = 0.f;
    for (int b = 0; b < 256; ++b) a += pstats[b * 256 + t];
    sums[t] = a;
    __syncthreads();
    if (t < 128) {
        float mu = sums[t] * (1.f / NN);
        float var = sums[128 + t] * (1.f / NN) - mu * mu;
        float sc = gamma[t] * rsqrtf(var + EPSV);
        ss[t] = sc;
        ss[128 + t] = beta[t] - mu * sc;
    }
}

// ---------------- Segmented pool (+BN/ReLU of layer 2) ----------------
// batch sorted: accumulate in-register while graph id unchanged; flush via
// atomicAdd on segment change. 64 rows per block.
__global__ __launch_bounds__(256) void k_pool(const float* __restrict__ A,
                                              const int* __restrict__ batch,
                                              const float* __restrict__ ss,
                                              float* __restrict__ pooled) {
    int t = threadIdx.x;
    int f = t & 127, half = t >> 7;
    int r0 = blockIdx.x * 64;
    int rend = min(r0 + 64, NN);
    float s = ss[f], h = ss[128 + f];
    float acc = 0.f;
    int cg = -1;
    for (int r = r0 + half; r < rend; r += 2) {
        int g = batch[r];
        if (g != cg) {
            if (cg >= 0) atomicAdd(&pooled[(size_t)cg * HD + f], acc);
            cg = g;
            acc = 0.f;
        }
        acc += fmaxf(A[(size_t)r * HD + f] * s + h, 0.f);
    }
    if (cg >= 0) atomicAdd(&pooled[(size_t)cg * HD + f], acc);
}

// ---------------- MLP head ----------------
__global__ __launch_bounds__(128) void k_mlp(const float* __restrict__ pooled,
                                             const int* __restrict__ batch,
                                             const float* __restrict__ gfeat,
                                             const float* __restrict__ M1w,
                                             const float* __restrict__ M1b,
                                             const float* __restrict__ M2w,
                                             const float* __restrict__ M2b,
                                             const float* __restrict__ M3w,
                                             const float* __restrict__ M3b,
                                             float* __restrict__ out) {
    __shared__ int sb[2];
    __shared__ float z[HD + GD];
    __shared__ float z1[MD];
    __shared__ float z2[MD / 2];
    int b = blockIdx.x, t = threadIdx.x;
    if (t < 2) {
        int val = b + t;
        int lo = 0, hi = NN;
        while (lo < hi) {
            int mid = (lo + hi) >> 1;
            if (batch[mid] < val) lo = mid + 1; else hi = mid;
        }
        sb[t] = lo;
    }
    __syncthreads();
    float ic = 1.f / fmaxf((float)(sb[1] - sb[0]), 1.f);
    z[t] = pooled[(size_t)b * HD + t] * ic;
    if (t < GD) z[HD + t] = gfeat[b * GD + t];
    __syncthreads();
    float a = M1b[t];
    for (int k = 0; k < HD + GD; ++k) a += z[k] * M1w[k * MD + t];
    z1[t] = fmaxf(a, 0.f);
    __syncthreads();
    if (t < MD / 2) {
        float a2 = M2b[t];
        for (int k = 0; k < MD; ++k) a2 += z1[k] * M2w[k * (MD / 2) + t];
        z2[t] = fmaxf(a2, 0.f);
    }
    __syncthreads();
    if (t < 64) {
        float p = z2[t] * M3w[t];
#pragma unroll
        for (int off = 32; off; off >>= 1) p += __shfl_down(p, off);
        if (t == 0) out[b] = p + M3b[0];
    }
}

static inline size_t alg(size_t x) { return (x + 255) & ~(size_t)255; }

extern "C" void kernel_launch(void* const* d_in, const int* in_sizes, int n_in,
                              void* d_out, int out_size, void* d_ws, size_t ws_size,
                              hipStream_t stream) {
    const float* x = (const float*)d_in[0];
    const int* ei = (const int*)d_in[1];
    const int* batch = (const int*)d_in[2];
    const float* gf = (const float*)d_in[3];
    const float* W[3] = {(const float*)d_in[4], (const float*)d_in[8], (const float*)d_in[12]};
    const float* bb[3] = {(const float*)d_in[5], (const float*)d_in[9], (const float*)d_in[13]};
    const float* gg[3] = {(const float*)d_in[6], (const float*)d_in[10], (const float*)d_in[14]};
    const float* be[3] = {(const float*)d_in[7], (const float*)d_in[11], (const float*)d_in[15]};
    const float* M1w = (const float*)d_in[16];
    const float* M1b = (const float*)d_in[17];
    const float* M2w = (const float*)d_in[18];
    const float* M2b = (const float*)d_in[19];
    const float* M3w = (const float*)d_in[20];
    const float* M3b = (const float*)d_in[21];
    float* out = (float*)d_out;

    char* w = (char*)d_ws;
    int* counts = (int*)w;        w += alg((size_t)NN * 4);
    int* bucket_cnt = (int*)w;    w += alg((size_t)NBK * 4);
    int* offsets = (int*)w;       w += alg((size_t)(NN + 1) * 4);
    int* csr = (int*)w;           w += alg((size_t)NE * 4);
    float* dinv = (float*)w;      w += alg((size_t)NN * 4);
    int* bsum = (int*)w;          w += alg((size_t)SCB * 4);
    int* bpre = (int*)w;          w += alg((size_t)SCB * 4);
    float* pstats = (float*)w;    w += alg((size_t)256 * 256 * 4);
    float* ss = (float*)w;        w += alg(256 * 4);
    float* pooled = (float*)w;    w += alg((size_t)BG * HD * 4);
    unsigned short* Wt = (unsigned short*)w;  w += alg((size_t)3 * 16384 * 2);
    unsigned int* binned = (unsigned int*)w;  w += alg((size_t)NBK * BCAP * 4);
    float* A = (float*)w;         w += alg((size_t)NN * HD * 4);
    unsigned short* Th = (unsigned short*)w;  w += alg((size_t)NN * HD * 2);

    const int* src = ei;
    const int* dst = ei + NE;

    hipMemsetAsync(bucket_cnt, 0, (size_t)NBK * 4, stream);
    k_bin<<<(NE + 2047) / 2048, 256, 0, stream>>>(src, dst, bucket_cnt, binned);
    k_cnt<<<NBK, 256, 0, stream>>>(binned, bucket_cnt, counts);
    k_bsum<<<SCB, 256, 0, stream>>>(counts, bsum);
    k_bscan<<<1, 256, 0, stream>>>(bsum, bpre);
    k_offsets<<<SCB, 256, 0, stream>>>(counts, bpre, offsets, dinv);
    k_fill2<<<NBK, 256, 0, stream>>>(binned, bucket_cnt, offsets, csr);
    k_wtrans<<<3, 256, 0, stream>>>(W[0], W[1], W[2], Wt);

    const float* hin = x;
    for (int L = 0; L < 3; ++L) {
        k_gemm<<<(NN + 63) / 64, 256, 0, stream>>>(hin, Wt + (size_t)L * 16384, Th, ss,
                                                   dinv, L > 0);
        k_aggregate<<<(NN + 3) / 4, 256, 0, stream>>>((const uint2*)Th, offsets, csr,
                                                      dinv, bb[L], A);
        k_colstats<<<256, 256, 0, stream>>>(A, pstats);
        k_bnfinal<<<1, 256, 0, stream>>>(pstats, gg[L], be[L], ss);
        hin = A;
    }

    hipMemsetAsync(pooled, 0, (size_t)BG * HD * 4, stream);
    k_pool<<<(NN + 63) / 64, 256, 0, stream>>>(A, batch, ss, pooled);
    k_mlp<<<BG, 128, 0, stream>>>(pooled, batch, gf, M1w, M1b, M2w, M2b, M3w, M3b, out);
}

// Round 7
// 379.846 us; speedup vs baseline: 2.4483x; 1.1663x over previous
//
#include <hip/hip_runtime.h>

#define NN 50000
#define NE 800000
#define BG 512
#define HD 128
#define GD 32
#define MD 128
#define EPSV 1e-5f
#define NBK 256   // dst buckets
#define BSTR 196  // dst per bucket (196*256 = 50176 >= NN)
#define BCAP 4096 // edge capacity per bucket (mean 3136, sd ~56)
#define SP 136    // LDS row stride (shorts) for gemm tiles
#define CSB 512   // colstats blocks

typedef __attribute__((ext_vector_type(8))) short bf16x8;
typedef __attribute__((ext_vector_type(4))) float f32x4;

// bf16 helpers (RNE pack, cheap unpack)
static __device__ __forceinline__ unsigned short f2bf(float f) {
    unsigned int u = __float_as_uint(f);
    u += 0x7fffu + ((u >> 16) & 1u);
    return (unsigned short)(u >> 16);
}
static __device__ __forceinline__ float bf_lo(unsigned int v) {
    return __uint_as_float(v << 16);
}
static __device__ __forceinline__ float bf_hi(unsigned int v) {
    return __uint_as_float(v & 0xffff0000u);
}

// ---------------- Pass 1: bin edges by dst bucket ----------------
__global__ __launch_bounds__(256) void k_bin(const int* __restrict__ src,
                                             const int* __restrict__ dst,
                                             int* __restrict__ bucket_cnt,
                                             unsigned int* __restrict__ binned) {
    __shared__ int hcnt[NBK];
    __shared__ int hbase[NBK];
    int tid = threadIdx.x;
    int e0 = blockIdx.x * 2048;
    unsigned int pv[8];
    int bk[8], rk[8];
#pragma unroll
    for (int i = 0; i < 8; ++i) {
        int e = e0 + i * 256 + tid;
        if (e < NE) {
            int s = src[e];
            int d = dst[e];
            bk[i] = d / BSTR;
            pv[i] = ((unsigned int)(d - bk[i] * BSTR) << 16) | (unsigned int)s;
        } else {
            bk[i] = -1;
        }
    }
    hcnt[tid] = 0;
    __syncthreads();
#pragma unroll
    for (int i = 0; i < 8; ++i)
        if (bk[i] >= 0) rk[i] = atomicAdd(&hcnt[bk[i]], 1);
    __syncthreads();
    hbase[tid] = atomicAdd(&bucket_cnt[tid], hcnt[tid]);
    __syncthreads();
#pragma unroll
    for (int i = 0; i < 8; ++i)
        if (bk[i] >= 0)
            binned[(size_t)bk[i] * BCAP + hbase[bk[i]] + rk[i]] = pv[i];
}

// ---------------- scan bucket totals -> bucket exclusive prefixes ----------------
__global__ __launch_bounds__(256) void k_bscan(const int* __restrict__ bucket_cnt,
                                               int* __restrict__ bpre) {
    __shared__ int ls[NBK];
    int t = threadIdx.x;
    int v = bucket_cnt[t];
    ls[t] = v;
    __syncthreads();
    for (int off = 1; off < NBK; off <<= 1) {
        int cur = ls[t];
        int add = (t >= off) ? ls[t - off] : 0;
        __syncthreads();
        ls[t] = cur + add;
        __syncthreads();
    }
    bpre[t] = ls[t] - v;  // exclusive
}

// ---------------- per-bucket histogram + local scan -> offsets, dinv ----------------
__global__ __launch_bounds__(256) void k_cnt2(const unsigned int* __restrict__ binned,
                                              const int* __restrict__ bucket_cnt,
                                              const int* __restrict__ bpre,
                                              int* __restrict__ offsets,
                                              float* __restrict__ dinv) {
    __shared__ int h[BSTR];
    __shared__ int ls[256];
    int b = blockIdx.x, t = threadIdx.x;
    if (t < BSTR) h[t] = 0;
    __syncthreads();
    int nb = bucket_cnt[b];
    const unsigned int* base = binned + (size_t)b * BCAP;
    for (int e = t; e < nb; e += 256)
        atomicAdd(&h[base[e] >> 16], 1);
    __syncthreads();
    int c = (t < BSTR) ? h[t] : 0;
    ls[t] = c;
    __syncthreads();
    for (int off = 1; off < 256; off <<= 1) {
        int cur = ls[t];
        int add = (t >= off) ? ls[t - off] : 0;
        __syncthreads();
        ls[t] = cur + add;
        __syncthreads();
    }
    int node = b * BSTR + t;
    if (t < BSTR && node < NN) {
        offsets[node] = ls[t] - c + bpre[b];
        dinv[node] = rsqrtf((float)(c + 1));  // in-degree + self loop
        if (node == NN - 1) offsets[NN] = NE;
    }
}

// ---------------- Pass 2: bucket-local CSR fill via LDS cursors ----------------
__global__ __launch_bounds__(256) void k_fill2(const unsigned int* __restrict__ binned,
                                               const int* __restrict__ bucket_cnt,
                                               const int* __restrict__ offsets,
                                               int* __restrict__ csr) {
    __shared__ int cur[BSTR];
    int b = blockIdx.x, t = threadIdx.x;
    int node = b * BSTR + t;
    if (t < BSTR) cur[t] = (node < NN) ? offsets[node] : 0;
    __syncthreads();
    int nb = bucket_cnt[b];
    const unsigned int* base = binned + (size_t)b * BCAP;
    for (int e = t; e < nb; e += 256) {
        unsigned int v = base[e];
        int pos = atomicAdd(&cur[v >> 16], 1);
        csr[pos] = (int)(v & 0xffffu);
    }
}

// ---------------- W pre-transpose: Wt[n][k] = bf16(W[k][n]), 3 layers ----------------
__global__ __launch_bounds__(256) void k_wtrans(const float* __restrict__ W0,
                                                const float* __restrict__ W1,
                                                const float* __restrict__ W2,
                                                unsigned short* __restrict__ Wt) {
    __shared__ unsigned short sW[128 * 130];
    const float* Wsrc = blockIdx.x == 0 ? W0 : (blockIdx.x == 1 ? W1 : W2);
#pragma unroll
    for (int i = 0; i < 64; ++i) {
        int idx = i * 256 + threadIdx.x;
        int k = idx >> 7, n = idx & 127;
        sW[n * 130 + k] = f2bf(Wsrc[idx]);
    }
    __syncthreads();
    unsigned short* o = Wt + (size_t)blockIdx.x * 16384;
#pragma unroll
    for (int i = 0; i < 64; ++i) {
        int idx = i * 256 + threadIdx.x;
        int n = idx >> 7, k = idx & 127;
        o[idx] = sW[n * 130 + k];
    }
}

// ---------------- MFMA GEMM: Th(bf16) = dinv[row] * (BNReLU?(In) @ W) ----------------
__global__ __launch_bounds__(256) void k_gemm(const float* __restrict__ In,
                                              const unsigned short* __restrict__ Wt,
                                              unsigned short* __restrict__ Th,
                                              const float* __restrict__ ss,
                                              const float* __restrict__ dinv,
                                              int useBN) {
    __shared__ unsigned short Abf[64 * SP];
    __shared__ unsigned short WtL[128 * SP];
    int tid = threadIdx.x;
    int rowBase = blockIdx.x * 64;
#pragma unroll
    for (int i = 0; i < 8; ++i) {
        int q = tid + i * 256;   // float4 units, 0..2047
        int row = q >> 5;
        int c4 = (q & 31) * 4;
        int rg = rowBase + row;
        if (rg >= NN) rg = NN - 1;
        float4 v = *(const float4*)&In[(size_t)rg * HD + c4];
        if (useBN) {
            float4 sc = *(const float4*)&ss[c4];
            float4 sh = *(const float4*)&ss[128 + c4];
            v.x = fmaxf(v.x * sc.x + sh.x, 0.f);
            v.y = fmaxf(v.y * sc.y + sh.y, 0.f);
            v.z = fmaxf(v.z * sc.z + sh.z, 0.f);
            v.w = fmaxf(v.w * sc.w + sh.w, 0.f);
        }
        unsigned short* p = &Abf[row * SP + c4];
        p[0] = f2bf(v.x); p[1] = f2bf(v.y); p[2] = f2bf(v.z); p[3] = f2bf(v.w);
    }
#pragma unroll
    for (int i = 0; i < 8; ++i) {
        int q = tid + i * 256;   // short8 units, 0..2047
        int n = q >> 4;
        int k8 = (q & 15) * 8;
        bf16x8 w = *(const bf16x8*)&Wt[n * HD + k8];
        *(bf16x8*)&WtL[n * SP + k8] = w;
    }
    __syncthreads();
    int lane = tid & 63;
    int wv = tid >> 6;
    int quad = lane >> 4;
    int lrow = wv * 16 + (lane & 15);
    f32x4 acc[8];
#pragma unroll
    for (int c = 0; c < 8; ++c) acc[c] = (f32x4){0.f, 0.f, 0.f, 0.f};
#pragma unroll
    for (int qk = 0; qk < 4; ++qk) {
        int ko = quad * 8 + qk * 32;
        bf16x8 bfr = *(const bf16x8*)&Abf[lrow * SP + ko];
#pragma unroll
        for (int c = 0; c < 8; ++c) {
            bf16x8 afr = *(const bf16x8*)&WtL[(c * 16 + (lane & 15)) * SP + ko];
            acc[c] = __builtin_amdgcn_mfma_f32_16x16x32_bf16(afr, bfr, acc[c], 0, 0, 0);
        }
    }
    int grow = rowBase + lrow;
    if (grow < NN) {
        float di = dinv[grow];
#pragma unroll
        for (int c = 0; c < 8; ++c) {
            ushort4 o;
            o.x = f2bf(acc[c][0] * di);
            o.y = f2bf(acc[c][1] * di);
            o.z = f2bf(acc[c][2] * di);
            o.w = f2bf(acc[c][3] * di);
            *(ushort4*)&Th[(size_t)grow * HD + c * 16 + quad * 4] = o;
        }
    }
}

// ---------------- Aggregate: A[d] = dinv[d]*(sum Ts[s] + Ts[d]) + b ----------------
// One wave per dst row; lane pair-split (lanes 0-31 even edges, 32-63 odd),
// uint2 per lane. 16-edge main loop = 8 loads in flight per lane.
__global__ __launch_bounds__(256, 8) void k_aggregate(const uint2* __restrict__ T2,
                                                      const int* __restrict__ offsets,
                                                      const int* __restrict__ csr,
                                                      const float* __restrict__ dinv,
                                                      const float* __restrict__ bias,
                                                      float* __restrict__ A) {
    int d = blockIdx.x * 4 + (threadIdx.x >> 6);
    int l = threadIdx.x & 63;
    int half = l >> 5;      // which edge of the pair
    int li = l & 31;        // uint2 index within row (features 4li..4li+3)
    if (d >= NN) return;
    int start = offsets[d], end = offsets[d + 1];
    float a0 = 0.f, a1 = 0.f, a2 = 0.f, a3 = 0.f;
    int j = start;
    for (; j + 15 < end; j += 16) {
        int s[8];
        uint2 v[8];
#pragma unroll
        for (int i = 0; i < 8; ++i) s[i] = csr[j + 2 * i + half];
#pragma unroll
        for (int i = 0; i < 8; ++i) v[i] = T2[(size_t)s[i] * 32 + li];
#pragma unroll
        for (int i = 0; i < 8; ++i) {
            a0 += bf_lo(v[i].x); a1 += bf_hi(v[i].x);
            a2 += bf_lo(v[i].y); a3 += bf_hi(v[i].y);
        }
    }
    for (; j + 7 < end; j += 8) {
        int s0 = csr[j + half];
        int s1 = csr[j + 2 + half];
        int s2 = csr[j + 4 + half];
        int s3 = csr[j + 6 + half];
        uint2 v0 = T2[(size_t)s0 * 32 + li];
        uint2 v1 = T2[(size_t)s1 * 32 + li];
        uint2 v2 = T2[(size_t)s2 * 32 + li];
        uint2 v3 = T2[(size_t)s3 * 32 + li];
        a0 += bf_lo(v0.x); a1 += bf_hi(v0.x); a2 += bf_lo(v0.y); a3 += bf_hi(v0.y);
        a0 += bf_lo(v1.x); a1 += bf_hi(v1.x); a2 += bf_lo(v1.y); a3 += bf_hi(v1.y);
        a0 += bf_lo(v2.x); a1 += bf_hi(v2.x); a2 += bf_lo(v2.y); a3 += bf_hi(v2.y);
        a0 += bf_lo(v3.x); a1 += bf_hi(v3.x); a2 += bf_lo(v3.y); a3 += bf_hi(v3.y);
    }
    for (; j + 1 < end; j += 2) {
        int s0 = csr[j + half];
        uint2 v0 = T2[(size_t)s0 * 32 + li];
        a0 += bf_lo(v0.x); a1 += bf_hi(v0.x); a2 += bf_lo(v0.y); a3 += bf_hi(v0.y);
    }
    if (j < end && half == 0) {
        int s0 = csr[j];
        uint2 v0 = T2[(size_t)s0 * 32 + li];
        a0 += bf_lo(v0.x); a1 += bf_hi(v0.x); a2 += bf_lo(v0.y); a3 += bf_hi(v0.y);
    }
    a0 += __shfl_xor(a0, 32);
    a1 += __shfl_xor(a1, 32);
    a2 += __shfl_xor(a2, 32);
    a3 += __shfl_xor(a3, 32);
    if (half == 0) {
        float di = dinv[d];
        uint2 vd = T2[(size_t)d * 32 + li];
        float4 bs = *(const float4*)&bias[4 * li];
        float4 o;
        o.x = di * (a0 + bf_lo(vd.x)) + bs.x;
        o.y = di * (a1 + bf_hi(vd.x)) + bs.y;
        o.z = di * (a2 + bf_lo(vd.y)) + bs.z;
        o.w = di * (a3 + bf_hi(vd.y)) + bs.w;
        *(float4*)&A[(size_t)d * HD + 4 * li] = o;
    }
}

// ---------------- BN stats: float4 loads, per-block partials ----------------
__global__ __launch_bounds__(256) void k_colstats(const float4* __restrict__ A4,
                                                  float* __restrict__ pstats) {
    int li = threadIdx.x & 31;   // float4 column (features 4li..4li+3)
    int rr = threadIdx.x >> 5;   // row subgroup (8)
    float4 s = {0.f, 0.f, 0.f, 0.f}, q = {0.f, 0.f, 0.f, 0.f};
    for (int row = blockIdx.x * 8 + rr; row < NN; row += gridDim.x * 8) {
        float4 v = A4[(size_t)row * 32 + li];
        s.x += v.x; s.y += v.y; s.z += v.z; s.w += v.w;
        q.x += v.x * v.x; q.y += v.y * v.y; q.z += v.z * v.z; q.w += v.w * v.w;
    }
    __shared__ float4 lsum[256], lqum[256];
    lsum[threadIdx.x] = s;
    lqum[threadIdx.x] = q;
    __syncthreads();
    if (rr == 0) {
        float4 a = lsum[li];
#pragma unroll
        for (int g = 1; g < 8; ++g) {
            float4 b = lsum[g * 32 + li];
            a.x += b.x; a.y += b.y; a.z += b.z; a.w += b.w;
        }
        *(float4*)&pstats[blockIdx.x * 256 + 4 * li] = a;
    } else if (rr == 1) {
        float4 a = lqum[li];
#pragma unroll
        for (int g = 1; g < 8; ++g) {
            float4 b = lqum[g * 32 + li];
            a.x += b.x; a.y += b.y; a.z += b.z; a.w += b.w;
        }
        *(float4*)&pstats[blockIdx.x * 256 + 128 + 4 * li] = a;
    }
}

__global__ __launch_bounds__(256) void k_bnfinal(const float* __restrict__ pstats,
                                                 const float* __restrict__ gamma,
                                                 const float* __restrict__ beta,
                                                 float* __restrict__ ss) {
    __shared__ float sums[256];
    int t = threadIdx.x;
    float a = 0.f;
    for (int b = 0; b < CSB; ++b) a += pstats[b * 256 + t];
    sums[t] = a;
    __syncthreads();
    if (t < 128) {
        float mu = sums[t] * (1.f / NN);
        float var = sums[128 + t] * (1.f / NN) - mu * mu;
        float sc = gamma[t] * rsqrtf(var + EPSV);
        ss[t] = sc;
        ss[128 + t] = beta[t] - mu * sc;
    }
}

// ---------------- Segmented pool (+BN/ReLU of layer 2) ----------------
__global__ __launch_bounds__(256) void k_pool(const float* __restrict__ A,
                                              const int* __restrict__ batch,
                                              const float* __restrict__ ss,
                                              float* __restrict__ pooled) {
    int t = threadIdx.x;
    int f = t & 127, half = t >> 7;
    int r0 = blockIdx.x * 64;
    int rend = min(r0 + 64, NN);
    float s = ss[f], h = ss[128 + f];
    float acc = 0.f;
    int cg = -1;
    for (int r = r0 + half; r < rend; r += 2) {
        int g = batch[r];
        if (g != cg) {
            if (cg >= 0) atomicAdd(&pooled[(size_t)cg * HD + f], acc);
            cg = g;
            acc = 0.f;
        }
        acc += fmaxf(A[(size_t)r * HD + f] * s + h, 0.f);
    }
    if (cg >= 0) atomicAdd(&pooled[(size_t)cg * HD + f], acc);
}

// ---------------- MLP head ----------------
__global__ __launch_bounds__(128) void k_mlp(const float* __restrict__ pooled,
                                             const int* __restrict__ batch,
                                             const float* __restrict__ gfeat,
                                             const float* __restrict__ M1w,
                                             const float* __restrict__ M1b,
                                             const float* __restrict__ M2w,
                                             const float* __restrict__ M2b,
                                             const float* __restrict__ M3w,
                                             const float* __restrict__ M3b,
                                             float* __restrict__ out) {
    __shared__ int sb[2];
    __shared__ float z[HD + GD];
    __shared__ float z1[MD];
    __shared__ float z2[MD / 2];
    int b = blockIdx.x, t = threadIdx.x;
    if (t < 2) {
        int val = b + t;
        int lo = 0, hi = NN;
        while (lo < hi) {
            int mid = (lo + hi) >> 1;
            if (batch[mid] < val) lo = mid + 1; else hi = mid;
        }
        sb[t] = lo;
    }
    __syncthreads();
    float ic = 1.f / fmaxf((float)(sb[1] - sb[0]), 1.f);
    z[t] = pooled[(size_t)b * HD + t] * ic;
    if (t < GD) z[HD + t] = gfeat[b * GD + t];
    __syncthreads();
    float a = M1b[t];
    for (int k = 0; k < HD + GD; ++k) a += z[k] * M1w[k * MD + t];
    z1[t] = fmaxf(a, 0.f);
    __syncthreads();
    if (t < MD / 2) {
        float a2 = M2b[t];
        for (int k = 0; k < MD; ++k) a2 += z1[k] * M2w[k * (MD / 2) + t];
        z2[t] = fmaxf(a2, 0.f);
    }
    __syncthreads();
    if (t < 64) {
        float p = z2[t] * M3w[t];
#pragma unroll
        for (int off = 32; off; off >>= 1) p += __shfl_down(p, off);
        if (t == 0) out[b] = p + M3b[0];
    }
}

static inline size_t alg(size_t x) { return (x + 255) & ~(size_t)255; }

extern "C" void kernel_launch(void* const* d_in, const int* in_sizes, int n_in,
                              void* d_out, int out_size, void* d_ws, size_t ws_size,
                              hipStream_t stream) {
    const float* x = (const float*)d_in[0];
    const int* ei = (const int*)d_in[1];
    const int* batch = (const int*)d_in[2];
    const float* gf = (const float*)d_in[3];
    const float* W[3] = {(const float*)d_in[4], (const float*)d_in[8], (const float*)d_in[12]};
    const float* bb[3] = {(const float*)d_in[5], (const float*)d_in[9], (const float*)d_in[13]};
    const float* gg[3] = {(const float*)d_in[6], (const float*)d_in[10], (const float*)d_in[14]};
    const float* be[3] = {(const float*)d_in[7], (const float*)d_in[11], (const float*)d_in[15]};
    const float* M1w = (const float*)d_in[16];
    const float* M1b = (const float*)d_in[17];
    const float* M2w = (const float*)d_in[18];
    const float* M2b = (const float*)d_in[19];
    const float* M3w = (const float*)d_in[20];
    const float* M3b = (const float*)d_in[21];
    float* out = (float*)d_out;

    char* w = (char*)d_ws;
    int* bucket_cnt = (int*)w;    w += alg((size_t)NBK * 4);
    int* bpre = (int*)w;          w += alg((size_t)NBK * 4);
    int* offsets = (int*)w;       w += alg((size_t)(NN + 1) * 4);
    int* csr = (int*)w;           w += alg((size_t)NE * 4);
    float* dinv = (float*)w;      w += alg((size_t)NN * 4);
    float* pstats = (float*)w;    w += alg((size_t)CSB * 256 * 4);
    float* ss = (float*)w;        w += alg(256 * 4);
    float* pooled = (float*)w;    w += alg((size_t)BG * HD * 4);
    unsigned short* Wt = (unsigned short*)w;  w += alg((size_t)3 * 16384 * 2);
    unsigned int* binned = (unsigned int*)w;  w += alg((size_t)NBK * BCAP * 4);
    float* A = (float*)w;         w += alg((size_t)NN * HD * 4);
    unsigned short* Th = (unsigned short*)w;  w += alg((size_t)NN * HD * 2);

    const int* src = ei;
    const int* dst = ei + NE;

    hipMemsetAsync(bucket_cnt, 0, (size_t)NBK * 4, stream);
    k_bin<<<(NE + 2047) / 2048, 256, 0, stream>>>(src, dst, bucket_cnt, binned);
    k_bscan<<<1, 256, 0, stream>>>(bucket_cnt, bpre);
    k_cnt2<<<NBK, 256, 0, stream>>>(binned, bucket_cnt, bpre, offsets, dinv);
    k_fill2<<<NBK, 256, 0, stream>>>(binned, bucket_cnt, offsets, csr);
    k_wtrans<<<3, 256, 0, stream>>>(W[0], W[1], W[2], Wt);

    const float* hin = x;
    for (int L = 0; L < 3; ++L) {
        k_gemm<<<(NN + 63) / 64, 256, 0, stream>>>(hin, Wt + (size_t)L * 16384, Th, ss,
                                                   dinv, L > 0);
        k_aggregate<<<(NN + 3) / 4, 256, 0, stream>>>((const uint2*)Th, offsets, csr,
                                                      dinv, bb[L], A);
        k_colstats<<<CSB, 256, 0, stream>>>((const float4*)A, pstats);
        k_bnfinal<<<1, 256, 0, stream>>>(pstats, gg[L], be[L], ss);
        hin = A;
    }

    hipMemsetAsync(pooled, 0, (size_t)BG * HD * 4, stream);
    k_pool<<<(NN + 63) / 64, 256, 0, stream>>>(A, batch, ss, pooled);
    k_mlp<<<BG, 128, 0, stream>>>(pooled, batch, gf, M1w, M1b, M2w, M2b, M3w, M3b, out);
}